// Round 3
// baseline (857.992 us; speedup 1.0000x reference)
//
#include <hip/hip_runtime.h>
#include <math.h>

#define NN 4
#define FC 32
#define DC 32
#define HH 480
#define WW 640
#define hh 120
#define ww 160
#define RR 20
#define TILE 14
#define ATT 16   // TILE+2 : conv1 output region (att pixels)
#define FT 18    // TILE+4 : feat / pooling region
#define BIAS_IDX 1282  // W//w//2 + (H//h//2)*W = 2 + 2*640
#define CP 16    // channel pairs (32 channels / 2)
#define ASTR 257 // dword stride per channel-pair in fallback attd overlay
#define LOGEPS -13.815511f   // log(1e-6)
#define MTHR   -8.0f         // mask threshold: valid logs are > -2.31, zeros are -13.8

// workspace layout (dword units):
// [0..20) num[r], [20..40) den[r]
// [64..)    w1t : 9*32*32 fp32      (fallback conv1)
// [9280..)  w2t : 9*32*4  fp32      (fallback conv2)
// [10432..) wB1 : 9*2*64*4 dwords   (conv1 MFMA B-fragments, bf16 pairs)
// [15040..) wB2 : 9*2*64*4 dwords   (conv2 MFMA B-fragments, hi/lo bf16 split, oc<4 valid)
// [20480..) rg   : RR*NN*hh*ww fp32 (log of pooled gt)
// [1556480..) pidx: RR*NN*hh*ww packed coords
// [3092480..) xb : NN*HH*WW*16 dwords (bf16 channel-pairs, channel-last)
#define WS_W1T 64
#define WS_W2T 9280
#define WS_WB1 10432
#define WS_WB2 15040
#define WS_RG  20480
#define WS_IDX 1556480
#define WS_XB  3092480
#define XB_COUNT ((size_t)NN * HH * WW * 16)
#define WS_NEED_BYTES (((size_t)WS_XB + XB_COUNT) * 4)

typedef __attribute__((ext_vector_type(8))) short short8;
typedef __attribute__((ext_vector_type(4))) float f32x4;
typedef __attribute__((ext_vector_type(2))) float f32x2;

__device__ __forceinline__ unsigned int bf16pack(float a, float b) {
    unsigned int ua = __float_as_uint(a);
    ua = (ua + 0x7fffu + ((ua >> 16) & 1u)) >> 16;
    unsigned int ub = __float_as_uint(b);
    ub = (ub + 0x7fffu + ((ub >> 16) & 1u)) >> 16;
    return ua | (ub << 16);
}
__device__ __forceinline__ unsigned short bf16r(float f) {
    unsigned int u = __float_as_uint(f);
    u = (u + 0x7fffu + ((u >> 16) & 1u)) >> 16;
    return (unsigned short)u;
}
__device__ __forceinline__ float bf16tof(unsigned short s) {
    return __uint_as_float(((unsigned int)s) << 16);
}

__global__ void prep_kernel(const float* __restrict__ W_att, const float* __restrict__ W_post,
                            float* __restrict__ ws) {
    int tid = threadIdx.x;
    if (tid < 2*RR) ws[tid] = 0.f;
    float* w1t = ws + WS_W1T;
    float* w2t = ws + WS_W2T;
    for (int i = tid; i < 32*32*9; i += blockDim.x) {
        int oc = i / (32*9); int rem = i % (32*9); int c = rem / 9; int tap = rem % 9;
        w1t[(tap*32 + c)*32 + oc] = W_att[i];
    }
    for (int i = tid; i < 4*32*9; i += blockDim.x) {
        int oc = i / (32*9); int rem = i % (32*9); int c = rem / 9; int tap = rem % 9;
        w2t[(tap*32 + c)*4 + oc] = W_post[i];
    }
    // conv1 MFMA B-fragments: B[k=c][n=oc] for 16x16x32 bf16.
    // lane: n = lane&15, k-slice = 8*(lane>>4)+j ; dword j packs (c0, c0+1)
    unsigned int* wb = (unsigned int*)(ws + WS_WB1);
    for (int i = tid; i < 9*2*64; i += blockDim.x) {
        int lane = i & 63; int th = i >> 6;
        int t = th >> 1, h2 = th & 1;
        int q = lane >> 4, col = lane & 15, oc = h2*16 + col;
        unsigned int vv[4];
        #pragma unroll
        for (int j = 0; j < 4; ++j) {
            int c0 = 8*q + 2*j;
            float f0 = W_att[(oc*32 + c0    )*9 + t];
            float f1 = W_att[(oc*32 + c0 + 1)*9 + t];
            vv[j] = bf16pack(f0, f1);
        }
        uint4 v4; v4.x = vv[0]; v4.y = vv[1]; v4.z = vv[2]; v4.w = vv[3];
        ((uint4*)wb)[i] = v4;
    }
    // conv2 MFMA B-fragments, hi/lo bf16 split (w = hi + lo, lo = w - float(hi)).
    // th = t*2 + part (part 0 = hi, 1 = lo); only oc<4 columns valid (rest zero).
    unsigned int* wb2 = (unsigned int*)(ws + WS_WB2);
    for (int i = tid; i < 9*2*64; i += blockDim.x) {
        int lane = i & 63; int th = i >> 6;
        int t = th >> 1, part = th & 1;
        int q = lane >> 4, oc = lane & 15;
        unsigned int vv[4];
        #pragma unroll
        for (int j = 0; j < 4; ++j) {
            int c0 = 8*q + 2*j;
            float f0 = (oc < 4) ? W_post[(oc*32 + c0    )*9 + t] : 0.f;
            float f1 = (oc < 4) ? W_post[(oc*32 + c0 + 1)*9 + t] : 0.f;
            if (part == 0) {
                vv[j] = ((unsigned int)bf16r(f0)) | (((unsigned int)bf16r(f1)) << 16);
            } else {
                float l0 = f0 - bf16tof(bf16r(f0));
                float l1 = f1 - bf16tof(bf16r(f1));
                vv[j] = ((unsigned int)bf16r(l0)) | (((unsigned int)bf16r(l1)) << 16);
            }
        }
        uint4 v4; v4.x = vv[0]; v4.y = vv[1]; v4.z = vv[2]; v4.w = vv[3];
        ((uint4*)wb2)[i] = v4;
    }
}

// x[n][c][y][:] fp32  ->  xb[n][y][x][cp] bf16-pair, channel-last (64B per pixel)
__global__ void xpack_kernel(const float* __restrict__ x, unsigned int* __restrict__ xb) {
    const int y = blockIdx.x;
    const int n = blockIdx.y;
    for (int px = threadIdx.x; px < WW; px += 256) {
        unsigned int* o = xb + ((size_t)(n*HH + y)*WW + px) * 16;
        uint4 v[4];
        #pragma unroll
        for (int k = 0; k < 4; ++k) {
            #pragma unroll
            for (int j = 0; j < 4; ++j) {
                int cp = 4*k + j;
                float f0 = x[((size_t)(n*FC + 2*cp    )*HH + y)*WW + px];
                float f1 = x[((size_t)(n*FC + 2*cp + 1)*HH + y)*WW + px];
                ((unsigned int*)&v[k])[j] = bf16pack(f0, f1);
            }
        }
        #pragma unroll
        for (int k = 0; k < 4; ++k) ((uint4*)o)[k] = v[k];
    }
}

// global random pooling: one thread per (h,w) cell.  Stores LOG of pooled gt
// (with the <0.1 -> 0 squash applied), so the main kernel's loss epilogue
// needs no logf and derives the mask from a threshold compare.
__global__ void pool_kernel(const float* __restrict__ gts, const float* __restrict__ rnd,
                            float* __restrict__ ws) {
    const int r = blockIdx.z, n = blockIdx.y;
    const int cell = blockIdx.x * 256 + threadIdx.x;
    const int h = cell / ww, w = cell % ww;
    const float* gt_n = gts + (size_t)n * HH * WW;
    const float* rd_n = rnd + ((size_t)r * NN + n) * (size_t)(HH * WW);
    float best = -1.f, bg = 0.f; int bii = 0, bjj = 0;
    #pragma unroll
    for (int bi = 0; bi < 4; ++bi) {
        const float4 g4 = *(const float4*)(gt_n + (size_t)(h*4 + bi)*WW + w*4);
        const float4 r4 = *(const float4*)(rd_n + (size_t)(h*4 + bi)*WW + w*4);
        const float gv[4] = {g4.x, g4.y, g4.z, g4.w};
        const float rv[4] = {r4.x, r4.y, r4.z, r4.w};
        #pragma unroll
        for (int bj = 0; bj < 4; ++bj) {
            float rm = (gv[bj] > 0.1f) ? rv[bj] : 0.f;
            if (rm > best) { best = rm; bii = bi; bjj = bj; bg = gv[bj]; }
        }
    }
    int idx_b = (h*4 + bii) * WW + (w*4 + bjj) + BIAS_IDX;
    size_t o = ((size_t)(r*NN + n) * (hh*ww)) + cell;
    float g2 = (bg < 0.1f) ? 0.f : bg;
    ((float*)(ws + WS_RG))[o] = logf(g2 + 1e-6f);
    ((unsigned int*)(ws + WS_IDX))[o] = ((unsigned int)(idx_b / WW) << 16) | (unsigned int)(idx_b % WW);
}

// s_feat chunk swizzle: pixel p's 16B chunk k lives at slot (k ^ ((p>>1)&3)).
// Spreads ds_read_b128 across bank groups (2-way = free) without the +4 dword pad,
// shrinking LDS 25.9 -> 20.7 KB so 7 blocks/CU fit.
__launch_bounds__(256, 7)
__global__ void wvl_main(const unsigned int* __restrict__ xb, const float* __restrict__ d,
                         const float* __restrict__ b_att, const float* __restrict__ b_post,
                         float* __restrict__ ws) {
    // s_feat: phase A = feat, channel-last [pix][16] (FT*FT pixels, chunk-swizzled).
    // phase B (overlay) = att*d, channel-last [pix][16] (ATT*ATT pixels) -> conv2 A-frags.
    __shared__ unsigned int s_feat[FT * FT * 16];   // 5184 dwords = 20.7 KB
    __shared__ float s_plog[FT * FT];
    __shared__ float s_rn[4], s_rd[4];

    const float* lg_all  = (const float*)(ws + WS_RG);
    const unsigned int* pidx_all = (const unsigned int*)(ws + WS_IDX);

    const int tid = threadIdx.x;

    // ---- XCD-locality swizzle ----
    // 72 groups of 120 blocks, group = (n, ty, tx-half); group g pinned to XCD g%8,
    // 9 groups per XCD.  Each group's unique xb region ~1.7 MB -> L2-resident.
    const int f   = blockIdx.x;        // 0..8639
    const int xcd = f & 7;
    const int bb  = f >> 3;            // 0..1079 : slot within xcd
    const int gi  = bb / 120;          // group slot 0..8
    const int ii  = bb % 120;          // index within group
    const int band = gi * 8 + xcd;     // 0..71
    const int n   = band / 18;
    const int rem = band % 18;
    const int ty  = rem >> 1;
    const int tx  = (rem & 1) * 6 + (ii % 6);
    const int r   = ii / 6;

    const int py0 = ty * TILE - 2;
    const int px0 = tx * TILE - 2;

    const size_t pbase = (size_t)(r*NN + n) * (hh*ww);

    // ------- Stage 1: stage log-gt tile (18x18) into LDS -------
    for (int p = tid; p < FT * FT; p += 256) {
        int pi = p / FT, pj = p % FT;
        int gi2 = py0 + pi, gj = px0 + pj;
        float lval = LOGEPS;
        if (gi2 >= 0 && gi2 < hh && gj >= 0 && gj < ww)
            lval = lg_all[pbase + (size_t)gi2 * ww + gj];
        s_plog[p] = lval;
    }

    // ------- Stage 2: bilinear gather from packed bf16 x -> channel-last LDS -------
    // (pidx read straight from global; packed f32x2 math for the 4-corner blend)
    for (int p = tid; p < FT * FT; p += 256) {
        int pi = p / FT, pj = p % FT;
        int gi2 = py0 + pi, gj = px0 + pj;
        unsigned int* dst = &s_feat[p * 16];
        const int sw = (p >> 1) & 3;
        if (gi2 < 0 || gi2 >= hh || gj < 0 || gj >= ww) {
            uint4 z; z.x = z.y = z.z = z.w = 0u;
            #pragma unroll
            for (int k = 0; k < 4; ++k) ((uint4*)dst)[k] = z;   // zeros: slot order moot
            continue;
        }
        unsigned int pk = pidx_all[pbase + (size_t)gi2 * ww + gj];
        int rr2 = (int)(pk >> 16);
        int cc  = (int)(pk & 0xffff);
        float gxf = 2.0f * ((float)cc  / (float)WW - 0.5f);
        float gyf = 2.0f * ((float)rr2 / (float)HH - 0.5f);
        float ix = (gxf + 1.0f) * 0.5f * (float)(WW - 1);
        float iy = (gyf + 1.0f) * 0.5f * (float)(HH - 1);
        float x0f = floorf(ix), y0f = floorf(iy);
        float wx = ix - x0f, wy = iy - y0f;
        int x0 = (int)x0f, y0 = (int)y0f;
        float vx0 = (x0f >= 0.f        && x0f <= (float)(WW-1)) ? 1.f : 0.f;
        float vx1 = (x0f + 1.f >= 0.f  && x0f + 1.f <= (float)(WW-1)) ? 1.f : 0.f;
        float vy0 = (y0f >= 0.f        && y0f <= (float)(HH-1)) ? 1.f : 0.f;
        float vy1 = (y0f + 1.f >= 0.f  && y0f + 1.f <= (float)(HH-1)) ? 1.f : 0.f;
        int xi0 = min(max(x0, 0), WW-1),  xi1 = min(max(x0+1, 0), WW-1);
        int yi0 = min(max(y0, 0), HH-1),  yi1 = min(max(y0+1, 0), HH-1);
        float w00 = (1.f-wx)*(1.f-wy) * (vx0*vy0);
        float w10 = wx*(1.f-wy)       * (vx1*vy0);
        float w01 = (1.f-wx)*wy       * (vx0*vy1);
        float w11 = wx*wy             * (vx1*vy1);
        const f32x2 vw00 = {w00, w00}, vw10 = {w10, w10}, vw01 = {w01, w01}, vw11 = {w11, w11};
        const uint4* q00 = (const uint4*)(xb + ((size_t)(n*HH + yi0)*WW + xi0) * 16);
        const uint4* q10 = (const uint4*)(xb + ((size_t)(n*HH + yi0)*WW + xi1) * 16);
        const uint4* q01 = (const uint4*)(xb + ((size_t)(n*HH + yi1)*WW + xi0) * 16);
        const uint4* q11 = (const uint4*)(xb + ((size_t)(n*HH + yi1)*WW + xi1) * 16);
        #pragma unroll
        for (int k = 0; k < 4; ++k) {
            uint4 A = q00[k], B = q10[k], C = q01[k], D = q11[k];
            uint4 o;
            #pragma unroll
            for (int j = 0; j < 4; ++j) {
                unsigned int ua = ((const unsigned int*)&A)[j];
                unsigned int ub = ((const unsigned int*)&B)[j];
                unsigned int uc = ((const unsigned int*)&C)[j];
                unsigned int ud = ((const unsigned int*)&D)[j];
                f32x2 va = {__uint_as_float(ua << 16), __uint_as_float(ua & 0xffff0000u)};
                f32x2 vb = {__uint_as_float(ub << 16), __uint_as_float(ub & 0xffff0000u)};
                f32x2 vc = {__uint_as_float(uc << 16), __uint_as_float(uc & 0xffff0000u)};
                f32x2 vd = {__uint_as_float(ud << 16), __uint_as_float(ud & 0xffff0000u)};
                f32x2 acc = vw00 * va;
                acc += vw10 * vb;
                acc += vw01 * vc;
                acc += vw11 * vd;
                ((unsigned int*)&o)[j] = bf16pack(acc.x, acc.y);
            }
            ((uint4*)dst)[k ^ sw] = o;
        }
    }
    __syncthreads();

    // ------- Stage 3: conv1 via MFMA 16x16x32 bf16 -------
    // wave wv handles att rows ay = wv*4 + rr. m = att col (lane&15), n = oc.
    const int lane = tid & 63;
    const int wv   = tid >> 6;
    const int mcol = lane & 15;
    const int q    = lane >> 4;

    f32x4 acc1[4][2];
    {
        float bb0 = b_att[mcol];
        float bb1 = b_att[mcol + 16];
        #pragma unroll
        for (int rr = 0; rr < 4; ++rr) {
            acc1[rr][0] = (f32x4){bb0, bb0, bb0, bb0};
            acc1[rr][1] = (f32x4){bb1, bb1, bb1, bb1};
        }
    }
    {
        const uint4* wB = (const uint4*)(ws + WS_WB1);
        #pragma unroll
        for (int t = 0; t < 9; ++t) {
            union { uint4 u; short8 s; } b0u, b1u;
            b0u.u = wB[(t*2 + 0)*64 + lane];
            b1u.u = wB[(t*2 + 1)*64 + lane];
            const int dy = t / 3, dx = t % 3;
            #pragma unroll
            for (int rr = 0; rr < 4; ++rr) {
                int ay = wv*4 + rr;
                int pix = (ay + dy) * FT + dx + mcol;
                union { uint4 u; short8 s; } a;
                a.u = *(const uint4*)&s_feat[pix * 16 + (q ^ ((pix >> 1) & 3)) * 4];
                acc1[rr][0] = __builtin_amdgcn_mfma_f32_16x16x32_bf16(a.s, b0u.s, acc1[rr][0], 0, 0, 0);
                acc1[rr][1] = __builtin_amdgcn_mfma_f32_16x16x32_bf16(a.s, b1u.s, acc1[rr][1], 0, 0, 0);
            }
        }
    }
    __syncthreads();   // all feat reads done; s_feat can be overlaid with att*d

    // ------- Stage 3b: sigmoid + *d, write att*d overlay (channel-last, pix-major) -------
    // conv1 D layout: oc = lane&15 (+16*h2), ax = 4*q + reg, row ay = wv*4+rr
    // overlay dword: pix*16 + ((oc>>3)^((pix>>1)&3))*4 + ((oc>>1)&3), half oc&1
    {
        unsigned short* attd16 = (unsigned short*)s_feat;
        #pragma unroll
        for (int rr = 0; rr < 4; ++rr) {
            int ay = wv*4 + rr;
            int gy = ty * TILE - 1 + ay;
            bool gyok = (gy >= 0 && gy < hh);
            #pragma unroll
            for (int h2 = 0; h2 < 2; ++h2) {
                int oc = mcol + 16*h2;
                const float* drow = d + ((size_t)(n*DC + oc) * hh + (gyok ? gy : 0)) * ww;
                #pragma unroll
                for (int reg = 0; reg < 4; ++reg) {
                    int ax = 4*q + reg;
                    int gx = tx * TILE - 1 + ax;
                    float av = __builtin_amdgcn_rcpf(1.f + __expf(-acc1[rr][h2][reg]));
                    float dv = (gyok && gx >= 0 && gx < ww) ? drow[gx] : 0.f;
                    int pix = ay * ATT + ax;
                    int dwi = pix * 16 + ((oc >> 3) ^ ((pix >> 1) & 3)) * 4 + ((oc >> 1) & 3);
                    attd16[dwi * 2 + (oc & 1)] = bf16r(av * dv);
                }
            }
        }
    }
    __syncthreads();

    // ------- Stage 4: conv2 via MFMA (N=4 valid cols, hi/lo weights) + smooth-L1 epilogue ----
    // wave wv owns output rows qy = wv*4+rr (valid qy<14).  A lane m = output col qx,
    // D: oc = lane&15 (valid <4), qx = 4*(lane>>4)+reg.
    float num_t = 0.f, den_t = 0.f;
    {
        const uint4* wB2 = (const uint4*)(ws + WS_WB2);
        const int qy0 = wv * 4;
        float bias2 = (mcol < 4) ? b_post[mcol] : 0.f;
        f32x4 acc2[4];
        #pragma unroll
        for (int rr = 0; rr < 4; ++rr) acc2[rr] = (f32x4){bias2, bias2, bias2, bias2};
        #pragma unroll
        for (int t = 0; t < 9; ++t) {
            union { uint4 u; short8 s; } bh, bl;
            bh.u = wB2[(t*2 + 0)*64 + lane];
            bl.u = wB2[(t*2 + 1)*64 + lane];
            const int dy = t / 3, dx = t % 3;
            #pragma unroll
            for (int rr = 0; rr < 4; ++rr) {
                if (qy0 + rr >= TILE) break;        // uniform per wave
                int pix = (qy0 + rr + dy) * ATT + (mcol + dx);  // cols 16,17 bleed -> masked rows
                union { uint4 u; short8 s; } a;
                a.u = *(const uint4*)&s_feat[pix * 16 + (q ^ ((pix >> 1) & 3)) * 4];
                acc2[rr] = __builtin_amdgcn_mfma_f32_16x16x32_bf16(a.s, bh.s, acc2[rr], 0, 0, 0);
                acc2[rr] = __builtin_amdgcn_mfma_f32_16x16x32_bf16(a.s, bl.s, acc2[rr], 0, 0, 0);
            }
        }
        // epilogue: lane computes its (qx, oc) contribution; neighbor offset is f(oc)
        const int o3 = mcol & 3;
        const int oy = (o3 == 0) ? 0 : 1;
        const int ox = (o3 == 3) ? -1 : ((o3 == 2) ? 0 : 1);
        #pragma unroll
        for (int rr = 0; rr < 4; ++rr) {
            if (qy0 + rr >= TILE) break;
            int qy = qy0 + rr;
            int gy2 = ty * TILE + qy;
            bool rowok = (gy2 < hh);
            #pragma unroll
            for (int reg = 0; reg < 4; ++reg) {
                int qx = 4*q + reg;
                int gx2 = tx * TILE + qx;
                float lc = s_plog[(qy + 2) * FT + (qx + 2)];
                float ln = s_plog[(qy + 2 + oy) * FT + (qx + 2 + ox)];
                bool m = rowok && (qx < TILE) && (gx2 < ww) && (mcol < 4)
                       && (lc > MTHR) && (ln > MTHR);
                float a2 = fabsf(acc2[rr][reg] - (lc - ln));
                float sl1 = (a2 < 0.01f) ? (50.f * a2 * a2) : (a2 - 0.005f);
                if (m) { num_t += sl1; den_t += 1.f; }
            }
        }
    }

    for (int off = 32; off > 0; off >>= 1) {
        num_t += __shfl_down(num_t, off);
        den_t += __shfl_down(den_t, off);
    }
    if (lane == 0) { s_rn[wv] = num_t; s_rd[wv] = den_t; }
    __syncthreads();
    if (tid == 0) {
        atomicAdd(&ws[r],      s_rn[0] + s_rn[1] + s_rn[2] + s_rn[3]);
        atomicAdd(&ws[RR + r], s_rd[0] + s_rd[1] + s_rd[2] + s_rd[3]);
    }
}

// ---------------- fallback (round-2 style, used if ws too small) ----------------
__launch_bounds__(256, 6)
__global__ void wvl_fallback(const float* __restrict__ x, const float* __restrict__ d,
                             const float* __restrict__ gts, const float* __restrict__ rnd,
                             const float* __restrict__ b_att, const float* __restrict__ b_post,
                             float* __restrict__ ws) {
    __shared__ unsigned int s_buf[CP * FT * FT];
    __shared__ float s_pgt[FT * FT];
    __shared__ int   s_pidx[FT * FT];
    __shared__ float s_rn[4], s_rd[4];

    const float* w1t = ws + WS_W1T;
    const float* w2t = ws + WS_W2T;

    const int tid = threadIdx.x;
    const int tilesx = (ww + TILE - 1) / TILE;
    const int tx = blockIdx.x % tilesx;
    const int ty = blockIdx.x / tilesx;
    const int n  = blockIdx.y;
    const int r  = blockIdx.z;
    const int py0 = ty * TILE - 2;
    const int px0 = tx * TILE - 2;

    const float* gt_n = gts + (size_t)n * HH * WW;
    const float* rd_n = rnd + ((size_t)r * NN + n) * (size_t)(HH * WW);
    for (int p = tid; p < FT * FT; p += 256) {
        int pi = p / FT, pj = p % FT;
        int gi = py0 + pi, gj = px0 + pj;
        float gval = 0.f; int idx = -1;
        if (gi >= 0 && gi < hh && gj >= 0 && gj < ww) {
            float best = -1.f; int bii = 0, bjj = 0; float bg = 0.f;
            #pragma unroll
            for (int bi = 0; bi < 4; ++bi) {
                const float* gr = gt_n + (size_t)(gi*4 + bi) * WW + gj*4;
                const float* rp = rd_n + (size_t)(gi*4 + bi) * WW + gj*4;
                #pragma unroll
                for (int bj = 0; bj < 4; ++bj) {
                    float g  = gr[bj];
                    float rv = rp[bj];
                    float rm = (g > 0.1f) ? rv : 0.f;
                    if (rm > best) { best = rm; bii = bi; bjj = bj; bg = g; }
                }
            }
            gval = bg;
            idx = (gi*4 + bii) * WW + (gj*4 + bjj) + BIAS_IDX;
        }
        s_pgt[p]  = gval;
        s_pidx[p] = idx;
    }
    __syncthreads();

    const float* x_n = x + (size_t)n * FC * HH * WW;
    for (int p = tid; p < FT * FT; p += 256) {
        int idx = s_pidx[p];
        if (idx < 0) {
            #pragma unroll
            for (int cp = 0; cp < CP; ++cp) s_buf[cp * (FT*FT) + p] = 0u;
            continue;
        }
        int cc = idx % WW;
        int rr2 = idx / WW;
        float gxf = 2.0f * ((float)cc  / (float)WW - 0.5f);
        float gyf = 2.0f * ((float)rr2 / (float)HH - 0.5f);
        float ix = (gxf + 1.0f) * 0.5f * (float)(WW - 1);
        float iy = (gyf + 1.0f) * 0.5f * (float)(HH - 1);
        float x0f = floorf(ix), y0f = floorf(iy);
        float wx = ix - x0f, wy = iy - y0f;
        int x0 = (int)x0f, y0 = (int)y0f;
        float vx0 = (x0f >= 0.f        && x0f <= (float)(WW-1)) ? 1.f : 0.f;
        float vx1 = (x0f + 1.f >= 0.f  && x0f + 1.f <= (float)(WW-1)) ? 1.f : 0.f;
        float vy0 = (y0f >= 0.f        && y0f <= (float)(HH-1)) ? 1.f : 0.f;
        float vy1 = (y0f + 1.f >= 0.f  && y0f + 1.f <= (float)(HH-1)) ? 1.f : 0.f;
        int xi0 = min(max(x0, 0), WW-1),  xi1 = min(max(x0+1, 0), WW-1);
        int yi0 = min(max(y0, 0), HH-1),  yi1 = min(max(y0+1, 0), HH-1);
        float w00 = (1.f-wx)*(1.f-wy) * (vx0*vy0);
        float w10 = wx*(1.f-wy)       * (vx1*vy0);
        float w01 = (1.f-wx)*wy       * (vx0*vy1);
        float w11 = wx*wy             * (vx1*vy1);
        const float* p00 = x_n + (size_t)yi0 * WW + xi0;
        const float* p10 = x_n + (size_t)yi0 * WW + xi1;
        const float* p01 = x_n + (size_t)yi1 * WW + xi0;
        const float* p11 = x_n + (size_t)yi1 * WW + xi1;
        #pragma unroll 4
        for (int cp = 0; cp < CP; ++cp) {
            int o0 = (2*cp)     * (HH * WW);
            int o1 = (2*cp + 1) * (HH * WW);
            float f0 = w00 * p00[o0] + w10 * p10[o0] + w01 * p01[o0] + w11 * p11[o0];
            float f1 = w00 * p00[o1] + w10 * p10[o1] + w01 * p01[o1] + w11 * p11[o1];
            s_buf[cp * (FT*FT) + p] = bf16pack(f0, f1);
        }
    }
    __syncthreads();

    const int ay = tid >> 4, ax = tid & 15;
    float acc[32];
    #pragma unroll
    for (int oc = 0; oc < 32; ++oc) acc[oc] = b_att[oc];
    for (int dy = 0; dy < 3; ++dy) {
        for (int dx = 0; dx < 3; ++dx) {
            const float* wt = w1t + (dy*3 + dx) * 1024;
            int base = (ay + dy) * FT + (ax + dx);
            for (int cp = 0; cp < CP; ++cp) {
                unsigned int u = s_buf[cp * (FT*FT) + base];
                float f0 = __uint_as_float(u << 16);
                float f1 = __uint_as_float(u & 0xffff0000u);
                const float* wp0 = wt + (2*cp) * 32;
                const float* wp1 = wp0 + 32;
                #pragma unroll
                for (int oc = 0; oc < 32; ++oc) acc[oc] = fmaf(f0, wp0[oc], acc[oc]);
                #pragma unroll
                for (int oc = 0; oc < 32; ++oc) acc[oc] = fmaf(f1, wp1[oc], acc[oc]);
            }
        }
    }
    __syncthreads();
    {
        int gy = ty * TILE - 1 + ay;
        int gx = tx * TILE - 1 + ax;
        bool inb = (gy >= 0 && gy < hh && gx >= 0 && gx < ww);
        const float* d_n = d + (size_t)n * DC * hh * ww;
        #pragma unroll
        for (int cp = 0; cp < CP; ++cp) {
            float a0 = 1.f / (1.f + __expf(-acc[2*cp]));
            float a1 = 1.f / (1.f + __expf(-acc[2*cp+1]));
            float v0 = 0.f, v1 = 0.f;
            if (inb) {
                v0 = a0 * d_n[(size_t)((2*cp)   * hh + gy) * ww + gx];
                v1 = a1 * d_n[(size_t)((2*cp+1) * hh + gy) * ww + gx];
            }
            s_buf[cp * (ATT*ATT) + tid] = bf16pack(v0, v1);
        }
    }
    __syncthreads();

    float num_t = 0.f, den_t = 0.f;
    if (tid < TILE * TILE) {
        int qy = tid / TILE, qx = tid % TILE;
        int gy2 = ty * TILE + qy, gx2 = tx * TILE + qx;
        if (gy2 < hh && gx2 < ww) {
            float acc2[4];
            #pragma unroll
            for (int k = 0; k < 4; ++k) acc2[k] = b_post[k];
            for (int dy = 0; dy < 3; ++dy) {
                for (int dx = 0; dx < 3; ++dx) {
                    const float* wt = w2t + (dy*3 + dx) * 128;
                    int base = (qy + dy) * ATT + (qx + dx);
                    for (int cp = 0; cp < CP; ++cp) {
                        unsigned int u = s_buf[cp * (ATT*ATT) + base];
                        float f0 = __uint_as_float(u << 16);
                        float f1 = __uint_as_float(u & 0xffff0000u);
                        const float* wp0 = wt + (2*cp) * 4;
                        const float* wp1 = wp0 + 4;
                        #pragma unroll
                        for (int k2 = 0; k2 < 4; ++k2) acc2[k2] = fmaf(f0, wp0[k2], acc2[k2]);
                        #pragma unroll
                        for (int k2 = 0; k2 < 4; ++k2) acc2[k2] = fmaf(f1, wp1[k2], acc2[k2]);
                    }
                }
            }
            int pc = (qy + 2) * FT + (qx + 2);
            float rgc = s_pgt[pc]; rgc = (rgc < 0.1f) ? 0.f : rgc;
            float lc = logf(rgc + 1e-6f);
            bool  mc = rgc > 0.1f;
            const int oys[4] = {0, 1, 1, 1};
            const int oxs[4] = {1, 1, 0, -1};
            #pragma unroll
            for (int k = 0; k < 4; ++k) {
                int pnb = (qy + 2 + oys[k]) * FT + (qx + 2 + oxs[k]);
                float rgn = s_pgt[pnb]; rgn = (rgn < 0.1f) ? 0.f : rgn;
                float ln = logf(rgn + 1e-6f);
                bool m = mc && (rgn > 0.1f);
                float gg = lc - ln;
                float a2 = fabsf(acc2[k] - gg);
                float sl1 = (a2 < 0.01f) ? (0.5f * a2 * a2 / 0.01f) : (a2 - 0.005f);
                if (m) { num_t += sl1; den_t += 1.f; }
            }
        }
    }
    for (int off = 32; off > 0; off >>= 1) {
        num_t += __shfl_down(num_t, off);
        den_t += __shfl_down(den_t, off);
    }
    int wid = tid >> 6, lane = tid & 63;
    if (lane == 0) { s_rn[wid] = num_t; s_rd[wid] = den_t; }
    __syncthreads();
    if (tid == 0) {
        atomicAdd(&ws[r],      s_rn[0] + s_rn[1] + s_rn[2] + s_rn[3]);
        atomicAdd(&ws[RR + r], s_rd[0] + s_rd[1] + s_rd[2] + s_rd[3]);
    }
}

__global__ void finish_kernel(const float* __restrict__ ws, float* __restrict__ out) {
    if (threadIdx.x == 0 && blockIdx.x == 0) {
        float s = 0.f;
        for (int r = 0; r < RR; ++r) s += ws[r] / ws[RR + r];
        out[0] = s / (float)RR;
    }
}

extern "C" void kernel_launch(void* const* d_in, const int* in_sizes, int n_in,
                              void* d_out, int out_size, void* d_ws, size_t ws_size,
                              hipStream_t stream) {
    const float* x      = (const float*)d_in[0];
    const float* d      = (const float*)d_in[1];
    const float* gts    = (const float*)d_in[2];
    const float* rnd    = (const float*)d_in[3];
    const float* W_att  = (const float*)d_in[4];
    const float* b_att  = (const float*)d_in[5];
    const float* W_post = (const float*)d_in[6];
    const float* b_post = (const float*)d_in[7];
    float* out = (float*)d_out;
    float* ws  = (float*)d_ws;

    hipLaunchKernelGGL(prep_kernel, dim3(1), dim3(1024), 0, stream, W_att, W_post, ws);

    const int tilesx = (ww + TILE - 1) / TILE;  // 12
    const int tilesy = (hh + TILE - 1) / TILE;  // 9

    if (ws_size >= WS_NEED_BYTES) {
        unsigned int* xb = (unsigned int*)(ws + WS_XB);
        hipLaunchKernelGGL(xpack_kernel, dim3(HH, NN), dim3(256), 0, stream, x, xb);
        hipLaunchKernelGGL(pool_kernel, dim3(hh*ww/256, NN, RR), dim3(256), 0, stream, gts, rnd, ws);
        // 1-D swizzled grid: 72 groups x 120 blocks = 8640 = tilesx*tilesy*NN*RR
        hipLaunchKernelGGL(wvl_main, dim3(tilesx * tilesy * NN * RR), dim3(256), 0, stream,
                           xb, d, b_att, b_post, ws);
    } else {
        dim3 grid2(tilesx * tilesy, NN, RR);
        hipLaunchKernelGGL(wvl_fallback, grid2, dim3(256), 0, stream,
                           x, d, gts, rnd, b_att, b_post, ws);
    }

    hipLaunchKernelGGL(finish_kernel, dim3(1), dim3(64), 0, stream, ws, out);
}

// Round 4
// 592.391 us; speedup vs baseline: 1.4484x; 1.4484x over previous
//
#include <hip/hip_runtime.h>
#include <math.h>

#define NN 4
#define FC 32
#define DC 32
#define HH 480
#define WW 640
#define hh 120
#define ww 160
#define RR 20
#define TILE 14
#define ATT 16   // TILE+2 : conv1 output region (att pixels)
#define FT 18    // TILE+4 : feat / pooling region
#define BIAS_IDX 1282  // W//w//2 + (H//h//2)*W = 2 + 2*640
#define CP 16    // channel pairs (32 channels / 2)
#define LOGEPS -13.815511f   // log(1e-6)
#define MTHR   -8.0f         // mask threshold: valid logs are > -2.31, zeros are -13.8

// workspace layout (dword units):
// [0..20) num[r], [20..40) den[r]
// [64..)    w1t : 9*32*32 fp32      (fallback conv1)
// [9280..)  w2t : 9*32*4  fp32      (fallback conv2)
// [10432..) wB1 : 9*2*64*4 dwords   (conv1 MFMA B-fragments, bf16 pairs)
// [15040..) wB2 : 9*2*64*4 dwords   (conv2 MFMA B-fragments, hi/lo bf16 split, oc<4 valid)
// [20480..) rg   : RR*NN*hh*ww fp32 (log of pooled gt)
// [1556480..) pidx: RR*NN*hh*ww packed coords
// [3092480..) xb : NN*HH*WW*16 dwords (bf16 channel-pairs, channel-last)
#define WS_W1T 64
#define WS_W2T 9280
#define WS_WB1 10432
#define WS_WB2 15040
#define WS_RG  20480
#define WS_IDX 1556480
#define WS_XB  3092480
#define XB_COUNT ((size_t)NN * HH * WW * 16)
#define WS_NEED_BYTES (((size_t)WS_XB + XB_COUNT) * 4)

// setup kernel block ranges
#define XPACK_B0 1
#define XPACK_NB (HH * NN)                 // 1920
#define POOL_B0  (XPACK_B0 + XPACK_NB)     // 1921
#define POOL_CB  (hh * ww / 256)           // 75 cell-blocks per (r,n)
#define POOL_NB  (POOL_CB * NN * RR)       // 6000
#define SETUP_NB (POOL_B0 + POOL_NB)       // 7921

typedef __attribute__((ext_vector_type(8))) short short8;
typedef __attribute__((ext_vector_type(4))) float f32x4;
typedef __attribute__((ext_vector_type(2))) float f32x2;

__device__ __forceinline__ unsigned int bf16pack(float a, float b) {
    unsigned int ua = __float_as_uint(a);
    ua = (ua + 0x7fffu + ((ua >> 16) & 1u)) >> 16;
    unsigned int ub = __float_as_uint(b);
    ub = (ub + 0x7fffu + ((ub >> 16) & 1u)) >> 16;
    return ua | (ub << 16);
}
__device__ __forceinline__ unsigned short bf16r(float f) {
    unsigned int u = __float_as_uint(f);
    u = (u + 0x7fffu + ((u >> 16) & 1u)) >> 16;
    return (unsigned short)u;
}
__device__ __forceinline__ float bf16tof(unsigned short s) {
    return __uint_as_float(((unsigned int)s) << 16);
}

// ---- merged setup: block 0 = weight prep, [1,1921) = xpack, [1921,7921) = pool ----
__global__ void setup_kernel(const float* __restrict__ x, const float* __restrict__ gts,
                             const float* __restrict__ rnd,
                             const float* __restrict__ W_att, const float* __restrict__ W_post,
                             float* __restrict__ ws) {
    const int b = blockIdx.x;
    const int tid = threadIdx.x;

    if (b == 0) {
        // ---- weight prep ----
        if (tid < 2*RR) ws[tid] = 0.f;
        float* w1t = ws + WS_W1T;
        float* w2t = ws + WS_W2T;
        for (int i = tid; i < 32*32*9; i += 256) {
            int oc = i / (32*9); int rem = i % (32*9); int c = rem / 9; int tap = rem % 9;
            w1t[(tap*32 + c)*32 + oc] = W_att[i];
        }
        for (int i = tid; i < 4*32*9; i += 256) {
            int oc = i / (32*9); int rem = i % (32*9); int c = rem / 9; int tap = rem % 9;
            w2t[(tap*32 + c)*4 + oc] = W_post[i];
        }
        // conv1 MFMA B-fragments: B[k=c][n=oc] for 16x16x32 bf16.
        unsigned int* wb = (unsigned int*)(ws + WS_WB1);
        for (int i = tid; i < 9*2*64; i += 256) {
            int lane = i & 63; int th = i >> 6;
            int t = th >> 1, h2 = th & 1;
            int q = lane >> 4, col = lane & 15, oc = h2*16 + col;
            unsigned int vv[4];
            #pragma unroll
            for (int j = 0; j < 4; ++j) {
                int c0 = 8*q + 2*j;
                float f0 = W_att[(oc*32 + c0    )*9 + t];
                float f1 = W_att[(oc*32 + c0 + 1)*9 + t];
                vv[j] = bf16pack(f0, f1);
            }
            uint4 v4; v4.x = vv[0]; v4.y = vv[1]; v4.z = vv[2]; v4.w = vv[3];
            ((uint4*)wb)[i] = v4;
        }
        // conv2 MFMA B-fragments, hi/lo bf16 split; only oc<4 columns valid.
        unsigned int* wb2 = (unsigned int*)(ws + WS_WB2);
        for (int i = tid; i < 9*2*64; i += 256) {
            int lane = i & 63; int th = i >> 6;
            int t = th >> 1, part = th & 1;
            int q = lane >> 4, oc = lane & 15;
            unsigned int vv[4];
            #pragma unroll
            for (int j = 0; j < 4; ++j) {
                int c0 = 8*q + 2*j;
                float f0 = (oc < 4) ? W_post[(oc*32 + c0    )*9 + t] : 0.f;
                float f1 = (oc < 4) ? W_post[(oc*32 + c0 + 1)*9 + t] : 0.f;
                if (part == 0) {
                    vv[j] = ((unsigned int)bf16r(f0)) | (((unsigned int)bf16r(f1)) << 16);
                } else {
                    float l0 = f0 - bf16tof(bf16r(f0));
                    float l1 = f1 - bf16tof(bf16r(f1));
                    vv[j] = ((unsigned int)bf16r(l0)) | (((unsigned int)bf16r(l1)) << 16);
                }
            }
            uint4 v4; v4.x = vv[0]; v4.y = vv[1]; v4.z = vv[2]; v4.w = vv[3];
            ((uint4*)wb2)[i] = v4;
        }
    } else if (b < POOL_B0) {
        // ---- xpack: x[n][c][y][:] fp32 -> xb[n][y][x][cp] bf16-pair (64B/pixel) ----
        const int bb = b - XPACK_B0;
        const int y = bb % HH;
        const int n = bb / HH;
        unsigned int* xb = (unsigned int*)(ws + WS_XB);
        for (int px = tid; px < WW; px += 256) {
            unsigned int* o = xb + ((size_t)(n*HH + y)*WW + px) * 16;
            uint4 v[4];
            #pragma unroll
            for (int k = 0; k < 4; ++k) {
                #pragma unroll
                for (int j = 0; j < 4; ++j) {
                    int cp = 4*k + j;
                    float f0 = x[((size_t)(n*FC + 2*cp    )*HH + y)*WW + px];
                    float f1 = x[((size_t)(n*FC + 2*cp + 1)*HH + y)*WW + px];
                    ((unsigned int*)&v[k])[j] = bf16pack(f0, f1);
                }
            }
            #pragma unroll
            for (int k = 0; k < 4; ++k) ((uint4*)o)[k] = v[k];
        }
    } else {
        // ---- pool: one thread per (h,w) cell; store log(pooled gt) + packed coords ----
        const int bb = b - POOL_B0;
        const int r  = bb / (POOL_CB * NN);
        const int rem = bb % (POOL_CB * NN);
        const int n  = rem / POOL_CB;
        const int cb = rem % POOL_CB;
        const int cell = cb * 256 + tid;
        const int h = cell / ww, w = cell % ww;
        const float* gt_n = gts + (size_t)n * HH * WW;
        const float* rd_n = rnd + ((size_t)r * NN + n) * (size_t)(HH * WW);
        float best = -1.f, bg = 0.f; int bii = 0, bjj = 0;
        #pragma unroll
        for (int bi = 0; bi < 4; ++bi) {
            const float4 g4 = *(const float4*)(gt_n + (size_t)(h*4 + bi)*WW + w*4);
            const float4 r4 = *(const float4*)(rd_n + (size_t)(h*4 + bi)*WW + w*4);
            const float gv[4] = {g4.x, g4.y, g4.z, g4.w};
            const float rv[4] = {r4.x, r4.y, r4.z, r4.w};
            #pragma unroll
            for (int bj = 0; bj < 4; ++bj) {
                float rm = (gv[bj] > 0.1f) ? rv[bj] : 0.f;
                if (rm > best) { best = rm; bii = bi; bjj = bj; bg = gv[bj]; }
            }
        }
        int idx_b = (h*4 + bii) * WW + (w*4 + bjj) + BIAS_IDX;
        size_t o = ((size_t)(r*NN + n) * (hh*ww)) + cell;
        float g2 = (bg < 0.1f) ? 0.f : bg;
        ((float*)(ws + WS_RG))[o] = logf(g2 + 1e-6f);
        ((unsigned int*)(ws + WS_IDX))[o] = ((unsigned int)(idx_b / WW) << 16) | (unsigned int)(idx_b % WW);
    }
}

// s_feat chunk swizzle: pixel p's 16B chunk k lives at slot (k ^ ((p>>1)&3)).
// Spreads ds_read_b128 across bank groups without the +4 dword pad (LDS 20.7 KB).
// launch_bounds kept at 5 waves/EU: the kernel's unified VGPR+AGPR working set is
// ~96 regs (acc1 32 + acc2 16 + ~48 arch); 512/5=102 fits, 512/7=73 spilled to
// scratch (round-3 regression: WRITE_SIZE 17->653 MB).  Do not raise past 5.
__launch_bounds__(256, 5)
__global__ void wvl_main(const unsigned int* __restrict__ xb, const float* __restrict__ d,
                         const float* __restrict__ b_att, const float* __restrict__ b_post,
                         float* __restrict__ ws) {
    // s_feat: phase A = feat, channel-last [pix][16] (FT*FT pixels, chunk-swizzled).
    // phase B (overlay) = att*d, channel-last [pix][16] (ATT*ATT pixels) -> conv2 A-frags.
    __shared__ unsigned int s_feat[FT * FT * 16];   // 5184 dwords = 20.7 KB
    __shared__ float s_plog[FT * FT];
    __shared__ float s_rn[4], s_rd[4];

    const float* lg_all  = (const float*)(ws + WS_RG);
    const unsigned int* pidx_all = (const unsigned int*)(ws + WS_IDX);

    const int tid = threadIdx.x;

    // ---- XCD-locality swizzle ----
    // 72 groups of 120 blocks, group = (n, ty, tx-half); group g pinned to XCD g%8,
    // 9 groups per XCD.  Each group's unique xb region ~1.7 MB -> L2-resident.
    const int f   = blockIdx.x;        // 0..8639
    const int xcd = f & 7;
    const int bb  = f >> 3;            // 0..1079 : slot within xcd
    const int gi  = bb / 120;          // group slot 0..8
    const int ii  = bb % 120;          // index within group
    const int band = gi * 8 + xcd;     // 0..71
    const int n   = band / 18;
    const int rem = band % 18;
    const int ty  = rem >> 1;
    const int tx  = (rem & 1) * 6 + (ii % 6);
    const int r   = ii / 6;

    const int py0 = ty * TILE - 2;
    const int px0 = tx * TILE - 2;

    const size_t pbase = (size_t)(r*NN + n) * (hh*ww);

    // ------- Stage 1: stage log-gt tile (18x18) into LDS -------
    for (int p = tid; p < FT * FT; p += 256) {
        int pi = p / FT, pj = p % FT;
        int gi2 = py0 + pi, gj = px0 + pj;
        float lval = LOGEPS;
        if (gi2 >= 0 && gi2 < hh && gj >= 0 && gj < ww)
            lval = lg_all[pbase + (size_t)gi2 * ww + gj];
        s_plog[p] = lval;
    }

    // ------- Stage 2: bilinear gather from packed bf16 x -> channel-last LDS -------
    for (int p = tid; p < FT * FT; p += 256) {
        int pi = p / FT, pj = p % FT;
        int gi2 = py0 + pi, gj = px0 + pj;
        unsigned int* dst = &s_feat[p * 16];
        const int sw = (p >> 1) & 3;
        if (gi2 < 0 || gi2 >= hh || gj < 0 || gj >= ww) {
            uint4 z; z.x = z.y = z.z = z.w = 0u;
            #pragma unroll
            for (int k = 0; k < 4; ++k) ((uint4*)dst)[k] = z;   // zeros: slot order moot
            continue;
        }
        unsigned int pk = pidx_all[pbase + (size_t)gi2 * ww + gj];
        int rr2 = (int)(pk >> 16);
        int cc  = (int)(pk & 0xffff);
        float gxf = 2.0f * ((float)cc  / (float)WW - 0.5f);
        float gyf = 2.0f * ((float)rr2 / (float)HH - 0.5f);
        float ix = (gxf + 1.0f) * 0.5f * (float)(WW - 1);
        float iy = (gyf + 1.0f) * 0.5f * (float)(HH - 1);
        float x0f = floorf(ix), y0f = floorf(iy);
        float wx = ix - x0f, wy = iy - y0f;
        int x0 = (int)x0f, y0 = (int)y0f;
        float vx0 = (x0f >= 0.f        && x0f <= (float)(WW-1)) ? 1.f : 0.f;
        float vx1 = (x0f + 1.f >= 0.f  && x0f + 1.f <= (float)(WW-1)) ? 1.f : 0.f;
        float vy0 = (y0f >= 0.f        && y0f <= (float)(HH-1)) ? 1.f : 0.f;
        float vy1 = (y0f + 1.f >= 0.f  && y0f + 1.f <= (float)(HH-1)) ? 1.f : 0.f;
        int xi0 = min(max(x0, 0), WW-1),  xi1 = min(max(x0+1, 0), WW-1);
        int yi0 = min(max(y0, 0), HH-1),  yi1 = min(max(y0+1, 0), HH-1);
        float w00 = (1.f-wx)*(1.f-wy) * (vx0*vy0);
        float w10 = wx*(1.f-wy)       * (vx1*vy0);
        float w01 = (1.f-wx)*wy       * (vx0*vy1);
        float w11 = wx*wy             * (vx1*vy1);
        const f32x2 vw00 = {w00, w00}, vw10 = {w10, w10}, vw01 = {w01, w01}, vw11 = {w11, w11};
        const uint4* q00 = (const uint4*)(xb + ((size_t)(n*HH + yi0)*WW + xi0) * 16);
        const uint4* q10 = (const uint4*)(xb + ((size_t)(n*HH + yi0)*WW + xi1) * 16);
        const uint4* q01 = (const uint4*)(xb + ((size_t)(n*HH + yi1)*WW + xi0) * 16);
        const uint4* q11 = (const uint4*)(xb + ((size_t)(n*HH + yi1)*WW + xi1) * 16);
        #pragma unroll
        for (int k = 0; k < 4; ++k) {
            uint4 A = q00[k], B = q10[k], C = q01[k], D = q11[k];
            uint4 o;
            #pragma unroll
            for (int j = 0; j < 4; ++j) {
                unsigned int ua = ((const unsigned int*)&A)[j];
                unsigned int ub = ((const unsigned int*)&B)[j];
                unsigned int uc = ((const unsigned int*)&C)[j];
                unsigned int ud = ((const unsigned int*)&D)[j];
                f32x2 va = {__uint_as_float(ua << 16), __uint_as_float(ua & 0xffff0000u)};
                f32x2 vb = {__uint_as_float(ub << 16), __uint_as_float(ub & 0xffff0000u)};
                f32x2 vc = {__uint_as_float(uc << 16), __uint_as_float(uc & 0xffff0000u)};
                f32x2 vd = {__uint_as_float(ud << 16), __uint_as_float(ud & 0xffff0000u)};
                f32x2 acc = vw00 * va;
                acc += vw10 * vb;
                acc += vw01 * vc;
                acc += vw11 * vd;
                ((unsigned int*)&o)[j] = bf16pack(acc.x, acc.y);
            }
            ((uint4*)dst)[k ^ sw] = o;
        }
    }
    __syncthreads();

    // ------- Stage 3: conv1 via MFMA 16x16x32 bf16 -------
    // wave wv handles att rows ay = wv*4 + rr. m = att col (lane&15), n = oc.
    const int lane = tid & 63;
    const int wv   = tid >> 6;
    const int mcol = lane & 15;
    const int q    = lane >> 4;

    f32x4 acc1[4][2];
    {
        float bb0 = b_att[mcol];
        float bb1 = b_att[mcol + 16];
        #pragma unroll
        for (int rr = 0; rr < 4; ++rr) {
            acc1[rr][0] = (f32x4){bb0, bb0, bb0, bb0};
            acc1[rr][1] = (f32x4){bb1, bb1, bb1, bb1};
        }
    }
    {
        const uint4* wB = (const uint4*)(ws + WS_WB1);
        #pragma unroll
        for (int t = 0; t < 9; ++t) {
            union { uint4 u; short8 s; } b0u, b1u;
            b0u.u = wB[(t*2 + 0)*64 + lane];
            b1u.u = wB[(t*2 + 1)*64 + lane];
            const int dy = t / 3, dx = t % 3;
            #pragma unroll
            for (int rr = 0; rr < 4; ++rr) {
                int ay = wv*4 + rr;
                int pix = (ay + dy) * FT + dx + mcol;
                union { uint4 u; short8 s; } a;
                a.u = *(const uint4*)&s_feat[pix * 16 + (q ^ ((pix >> 1) & 3)) * 4];
                acc1[rr][0] = __builtin_amdgcn_mfma_f32_16x16x32_bf16(a.s, b0u.s, acc1[rr][0], 0, 0, 0);
                acc1[rr][1] = __builtin_amdgcn_mfma_f32_16x16x32_bf16(a.s, b1u.s, acc1[rr][1], 0, 0, 0);
            }
        }
    }
    __syncthreads();   // all feat reads done; s_feat can be overlaid with att*d

    // ------- Stage 3b: sigmoid + *d, write att*d overlay (channel-last, pix-major) -------
    // conv1 D layout: oc = lane&15 (+16*h2), ax = 4*q + reg, row ay = wv*4+rr
    // overlay dword: pix*16 + ((oc>>3)^((pix>>1)&3))*4 + ((oc>>1)&3), half oc&1
    {
        unsigned short* attd16 = (unsigned short*)s_feat;
        #pragma unroll
        for (int rr = 0; rr < 4; ++rr) {
            int ay = wv*4 + rr;
            int gy = ty * TILE - 1 + ay;
            bool gyok = (gy >= 0 && gy < hh);
            #pragma unroll
            for (int h2 = 0; h2 < 2; ++h2) {
                int oc = mcol + 16*h2;
                const float* drow = d + ((size_t)(n*DC + oc) * hh + (gyok ? gy : 0)) * ww;
                #pragma unroll
                for (int reg = 0; reg < 4; ++reg) {
                    int ax = 4*q + reg;
                    int gx = tx * TILE - 1 + ax;
                    float av = __builtin_amdgcn_rcpf(1.f + __expf(-acc1[rr][h2][reg]));
                    float dv = (gyok && gx >= 0 && gx < ww) ? drow[gx] : 0.f;
                    int pix = ay * ATT + ax;
                    int dwi = pix * 16 + ((oc >> 3) ^ ((pix >> 1) & 3)) * 4 + ((oc >> 1) & 3);
                    attd16[dwi * 2 + (oc & 1)] = bf16r(av * dv);
                }
            }
        }
    }
    __syncthreads();

    // ------- Stage 4: conv2 via MFMA (N=4 valid cols, hi/lo weights) + smooth-L1 epilogue ----
    // wave wv owns output rows qy = wv*4+rr (valid qy<14).  A lane m = output col qx,
    // D: oc = lane&15 (valid <4), qx = 4*(lane>>4)+reg.
    float num_t = 0.f, den_t = 0.f;
    {
        const uint4* wB2 = (const uint4*)(ws + WS_WB2);
        const int qy0 = wv * 4;
        float bias2 = (mcol < 4) ? b_post[mcol] : 0.f;
        f32x4 acc2[4];
        #pragma unroll
        for (int rr = 0; rr < 4; ++rr) acc2[rr] = (f32x4){bias2, bias2, bias2, bias2};
        #pragma unroll
        for (int t = 0; t < 9; ++t) {
            union { uint4 u; short8 s; } bh, bl;
            bh.u = wB2[(t*2 + 0)*64 + lane];
            bl.u = wB2[(t*2 + 1)*64 + lane];
            const int dy = t / 3, dx = t % 3;
            #pragma unroll
            for (int rr = 0; rr < 4; ++rr) {
                if (qy0 + rr >= TILE) break;        // uniform per wave
                int pix = (qy0 + rr + dy) * ATT + (mcol + dx);  // cols 16,17 bleed -> masked rows
                union { uint4 u; short8 s; } a;
                a.u = *(const uint4*)&s_feat[pix * 16 + (q ^ ((pix >> 1) & 3)) * 4];
                acc2[rr] = __builtin_amdgcn_mfma_f32_16x16x32_bf16(a.s, bh.s, acc2[rr], 0, 0, 0);
                acc2[rr] = __builtin_amdgcn_mfma_f32_16x16x32_bf16(a.s, bl.s, acc2[rr], 0, 0, 0);
            }
        }
        // epilogue: lane computes its (qx, oc) contribution; neighbor offset is f(oc)
        const int o3 = mcol & 3;
        const int oy = (o3 == 0) ? 0 : 1;
        const int ox = (o3 == 3) ? -1 : ((o3 == 2) ? 0 : 1);
        #pragma unroll
        for (int rr = 0; rr < 4; ++rr) {
            if (qy0 + rr >= TILE) break;
            int qy = qy0 + rr;
            int gy2 = ty * TILE + qy;
            bool rowok = (gy2 < hh);
            #pragma unroll
            for (int reg = 0; reg < 4; ++reg) {
                int qx = 4*q + reg;
                int gx2 = tx * TILE + qx;
                float lc = s_plog[(qy + 2) * FT + (qx + 2)];
                float ln = s_plog[(qy + 2 + oy) * FT + (qx + 2 + ox)];
                bool m = rowok && (qx < TILE) && (gx2 < ww) && (mcol < 4)
                       && (lc > MTHR) && (ln > MTHR);
                float a2 = fabsf(acc2[rr][reg] - (lc - ln));
                float sl1 = (a2 < 0.01f) ? (50.f * a2 * a2) : (a2 - 0.005f);
                if (m) { num_t += sl1; den_t += 1.f; }
            }
        }
    }

    for (int off = 32; off > 0; off >>= 1) {
        num_t += __shfl_down(num_t, off);
        den_t += __shfl_down(den_t, off);
    }
    if (lane == 0) { s_rn[wv] = num_t; s_rd[wv] = den_t; }
    __syncthreads();
    if (tid == 0) {
        atomicAdd(&ws[r],      s_rn[0] + s_rn[1] + s_rn[2] + s_rn[3]);
        atomicAdd(&ws[RR + r], s_rd[0] + s_rd[1] + s_rd[2] + s_rd[3]);
    }
}

// ---------------- fallback (used if ws too small) ----------------
__launch_bounds__(256, 6)
__global__ void wvl_fallback(const float* __restrict__ x, const float* __restrict__ d,
                             const float* __restrict__ gts, const float* __restrict__ rnd,
                             const float* __restrict__ b_att, const float* __restrict__ b_post,
                             float* __restrict__ ws) {
    __shared__ unsigned int s_buf[CP * FT * FT];
    __shared__ float s_pgt[FT * FT];
    __shared__ int   s_pidx[FT * FT];
    __shared__ float s_rn[4], s_rd[4];

    const float* w1t = ws + WS_W1T;
    const float* w2t = ws + WS_W2T;

    const int tid = threadIdx.x;
    const int tilesx = (ww + TILE - 1) / TILE;
    const int tx = blockIdx.x % tilesx;
    const int ty = blockIdx.x / tilesx;
    const int n  = blockIdx.y;
    const int r  = blockIdx.z;
    const int py0 = ty * TILE - 2;
    const int px0 = tx * TILE - 2;

    const float* gt_n = gts + (size_t)n * HH * WW;
    const float* rd_n = rnd + ((size_t)r * NN + n) * (size_t)(HH * WW);
    for (int p = tid; p < FT * FT; p += 256) {
        int pi = p / FT, pj = p % FT;
        int gi = py0 + pi, gj = px0 + pj;
        float gval = 0.f; int idx = -1;
        if (gi >= 0 && gi < hh && gj >= 0 && gj < ww) {
            float best = -1.f; int bii = 0, bjj = 0; float bg = 0.f;
            #pragma unroll
            for (int bi = 0; bi < 4; ++bi) {
                const float* gr = gt_n + (size_t)(gi*4 + bi) * WW + gj*4;
                const float* rp = rd_n + (size_t)(gi*4 + bi) * WW + gj*4;
                #pragma unroll
                for (int bj = 0; bj < 4; ++bj) {
                    float g  = gr[bj];
                    float rv = rp[bj];
                    float rm = (g > 0.1f) ? rv : 0.f;
                    if (rm > best) { best = rm; bii = bi; bjj = bj; bg = g; }
                }
            }
            gval = bg;
            idx = (gi*4 + bii) * WW + (gj*4 + bjj) + BIAS_IDX;
        }
        s_pgt[p]  = gval;
        s_pidx[p] = idx;
    }
    __syncthreads();

    const float* x_n = x + (size_t)n * FC * HH * WW;
    for (int p = tid; p < FT * FT; p += 256) {
        int idx = s_pidx[p];
        if (idx < 0) {
            #pragma unroll
            for (int cp = 0; cp < CP; ++cp) s_buf[cp * (FT*FT) + p] = 0u;
            continue;
        }
        int cc = idx % WW;
        int rr2 = idx / WW;
        float gxf = 2.0f * ((float)cc  / (float)WW - 0.5f);
        float gyf = 2.0f * ((float)rr2 / (float)HH - 0.5f);
        float ix = (gxf + 1.0f) * 0.5f * (float)(WW - 1);
        float iy = (gyf + 1.0f) * 0.5f * (float)(HH - 1);
        float x0f = floorf(ix), y0f = floorf(iy);
        float wx = ix - x0f, wy = iy - y0f;
        int x0 = (int)x0f, y0 = (int)y0f;
        float vx0 = (x0f >= 0.f        && x0f <= (float)(WW-1)) ? 1.f : 0.f;
        float vx1 = (x0f + 1.f >= 0.f  && x0f + 1.f <= (float)(WW-1)) ? 1.f : 0.f;
        float vy0 = (y0f >= 0.f        && y0f <= (float)(HH-1)) ? 1.f : 0.f;
        float vy1 = (y0f + 1.f >= 0.f  && y0f + 1.f <= (float)(HH-1)) ? 1.f : 0.f;
        int xi0 = min(max(x0, 0), WW-1),  xi1 = min(max(x0+1, 0), WW-1);
        int yi0 = min(max(y0, 0), HH-1),  yi1 = min(max(y0+1, 0), HH-1);
        float w00 = (1.f-wx)*(1.f-wy) * (vx0*vy0);
        float w10 = wx*(1.f-wy)       * (vx1*vy0);
        float w01 = (1.f-wx)*wy       * (vx0*vy1);
        float w11 = wx*wy             * (vx1*vy1);
        const float* p00 = x_n + (size_t)yi0 * WW + xi0;
        const float* p10 = x_n + (size_t)yi0 * WW + xi1;
        const float* p01 = x_n + (size_t)yi1 * WW + xi0;
        const float* p11 = x_n + (size_t)yi1 * WW + xi1;
        #pragma unroll 4
        for (int cp = 0; cp < CP; ++cp) {
            int o0 = (2*cp)     * (HH * WW);
            int o1 = (2*cp + 1) * (HH * WW);
            float f0 = w00 * p00[o0] + w10 * p10[o0] + w01 * p01[o0] + w11 * p11[o0];
            float f1 = w00 * p00[o1] + w10 * p10[o1] + w01 * p01[o1] + w11 * p11[o1];
            s_buf[cp * (FT*FT) + p] = bf16pack(f0, f1);
        }
    }
    __syncthreads();

    const int ay = tid >> 4, ax = tid & 15;
    float acc[32];
    #pragma unroll
    for (int oc = 0; oc < 32; ++oc) acc[oc] = b_att[oc];
    for (int dy = 0; dy < 3; ++dy) {
        for (int dx = 0; dx < 3; ++dx) {
            const float* wt = w1t + (dy*3 + dx) * 1024;
            int base = (ay + dy) * FT + (ax + dx);
            for (int cp = 0; cp < CP; ++cp) {
                unsigned int u = s_buf[cp * (FT*FT) + base];
                float f0 = __uint_as_float(u << 16);
                float f1 = __uint_as_float(u & 0xffff0000u);
                const float* wp0 = wt + (2*cp) * 32;
                const float* wp1 = wp0 + 32;
                #pragma unroll
                for (int oc = 0; oc < 32; ++oc) acc[oc] = fmaf(f0, wp0[oc], acc[oc]);
                #pragma unroll
                for (int oc = 0; oc < 32; ++oc) acc[oc] = fmaf(f1, wp1[oc], acc[oc]);
            }
        }
    }
    __syncthreads();
    {
        int gy = ty * TILE - 1 + ay;
        int gx = tx * TILE - 1 + ax;
        bool inb = (gy >= 0 && gy < hh && gx >= 0 && gx < ww);
        const float* d_n = d + (size_t)n * DC * hh * ww;
        #pragma unroll
        for (int cp = 0; cp < CP; ++cp) {
            float a0 = 1.f / (1.f + __expf(-acc[2*cp]));
            float a1 = 1.f / (1.f + __expf(-acc[2*cp+1]));
            float v0 = 0.f, v1 = 0.f;
            if (inb) {
                v0 = a0 * d_n[(size_t)((2*cp)   * hh + gy) * ww + gx];
                v1 = a1 * d_n[(size_t)((2*cp+1) * hh + gy) * ww + gx];
            }
            s_buf[cp * (ATT*ATT) + tid] = bf16pack(v0, v1);
        }
    }
    __syncthreads();

    float num_t = 0.f, den_t = 0.f;
    if (tid < TILE * TILE) {
        int qy = tid / TILE, qx = tid % TILE;
        int gy2 = ty * TILE + qy, gx2 = tx * TILE + qx;
        if (gy2 < hh && gx2 < ww) {
            float acc2[4];
            #pragma unroll
            for (int k = 0; k < 4; ++k) acc2[k] = b_post[k];
            for (int dy = 0; dy < 3; ++dy) {
                for (int dx = 0; dx < 3; ++dx) {
                    const float* wt = w2t + (dy*3 + dx) * 128;
                    int base = (qy + dy) * ATT + (qx + dx);
                    for (int cp = 0; cp < CP; ++cp) {
                        unsigned int u = s_buf[cp * (ATT*ATT) + base];
                        float f0 = __uint_as_float(u << 16);
                        float f1 = __uint_as_float(u & 0xffff0000u);
                        const float* wp0 = wt + (2*cp) * 4;
                        const float* wp1 = wp0 + 4;
                        #pragma unroll
                        for (int k2 = 0; k2 < 4; ++k2) acc2[k2] = fmaf(f0, wp0[k2], acc2[k2]);
                        #pragma unroll
                        for (int k2 = 0; k2 < 4; ++k2) acc2[k2] = fmaf(f1, wp1[k2], acc2[k2]);
                    }
                }
            }
            int pc = (qy + 2) * FT + (qx + 2);
            float rgc = s_pgt[pc]; rgc = (rgc < 0.1f) ? 0.f : rgc;
            float lc = logf(rgc + 1e-6f);
            bool  mc = rgc > 0.1f;
            const int oys[4] = {0, 1, 1, 1};
            const int oxs[4] = {1, 1, 0, -1};
            #pragma unroll
            for (int k = 0; k < 4; ++k) {
                int pnb = (qy + 2 + oys[k]) * FT + (qx + 2 + oxs[k]);
                float rgn = s_pgt[pnb]; rgn = (rgn < 0.1f) ? 0.f : rgn;
                float ln = logf(rgn + 1e-6f);
                bool m = mc && (rgn > 0.1f);
                float gg = lc - ln;
                float a2 = fabsf(acc2[k] - gg);
                float sl1 = (a2 < 0.01f) ? (0.5f * a2 * a2 / 0.01f) : (a2 - 0.005f);
                if (m) { num_t += sl1; den_t += 1.f; }
            }
        }
    }
    for (int off = 32; off > 0; off >>= 1) {
        num_t += __shfl_down(num_t, off);
        den_t += __shfl_down(den_t, off);
    }
    int wid = tid >> 6, lane = tid & 63;
    if (lane == 0) { s_rn[wid] = num_t; s_rd[wid] = den_t; }
    __syncthreads();
    if (tid == 0) {
        atomicAdd(&ws[r],      s_rn[0] + s_rn[1] + s_rn[2] + s_rn[3]);
        atomicAdd(&ws[RR + r], s_rd[0] + s_rd[1] + s_rd[2] + s_rd[3]);
    }
}

__global__ void finish_kernel(const float* __restrict__ ws, float* __restrict__ out) {
    if (threadIdx.x == 0 && blockIdx.x == 0) {
        float s = 0.f;
        for (int r = 0; r < RR; ++r) s += ws[r] / ws[RR + r];
        out[0] = s / (float)RR;
    }
}

extern "C" void kernel_launch(void* const* d_in, const int* in_sizes, int n_in,
                              void* d_out, int out_size, void* d_ws, size_t ws_size,
                              hipStream_t stream) {
    const float* x      = (const float*)d_in[0];
    const float* d      = (const float*)d_in[1];
    const float* gts    = (const float*)d_in[2];
    const float* rnd    = (const float*)d_in[3];
    const float* W_att  = (const float*)d_in[4];
    const float* b_att  = (const float*)d_in[5];
    const float* W_post = (const float*)d_in[6];
    const float* b_post = (const float*)d_in[7];
    float* out = (float*)d_out;
    float* ws  = (float*)d_ws;

    const int tilesx = (ww + TILE - 1) / TILE;  // 12
    const int tilesy = (hh + TILE - 1) / TILE;  // 9

    if (ws_size >= WS_NEED_BYTES) {
        hipLaunchKernelGGL(setup_kernel, dim3(SETUP_NB), dim3(256), 0, stream,
                           x, gts, rnd, W_att, W_post, ws);
        unsigned int* xb = (unsigned int*)(ws + WS_XB);
        // 1-D swizzled grid: 72 groups x 120 blocks = 8640 = tilesx*tilesy*NN*RR
        hipLaunchKernelGGL(wvl_main, dim3(tilesx * tilesy * NN * RR), dim3(256), 0, stream,
                           xb, d, b_att, b_post, ws);
    } else {
        hipLaunchKernelGGL(setup_kernel, dim3(1), dim3(256), 0, stream,
                           x, gts, rnd, W_att, W_post, ws);   // block 0 = weight prep only
        dim3 grid2(tilesx * tilesy, NN, RR);
        hipLaunchKernelGGL(wvl_fallback, grid2, dim3(256), 0, stream,
                           x, d, gts, rnd, b_att, b_post, ws);
    }

    hipLaunchKernelGGL(finish_kernel, dim3(1), dim3(64), 0, stream, ws, out);
}

// Round 5
// 580.970 us; speedup vs baseline: 1.4768x; 1.0197x over previous
//
#include <hip/hip_runtime.h>
#include <math.h>

#define NN 4
#define FC 32
#define DC 32
#define HH 480
#define WW 640
#define hh 120
#define ww 160
#define RR 20
#define TILE 14
#define ATT 16   // TILE+2 : conv1 output region (att pixels)
#define FT 18    // TILE+4 : feat / pooling region
#define BIAS_IDX 1282  // W//w//2 + (H//h//2)*W = 2 + 2*640
#define CP 16    // channel pairs (32 channels / 2)
#define LOGEPS -13.815511f   // log(1e-6)
#define MTHR   -8.0f         // mask threshold: valid logs are > -2.31, zeros are -13.8

// workspace layout (dword units):
// [0..40)   legacy num/den (unused by main path now)
// [64..)    w1t : 9*32*32 fp32      (fallback conv1)
// [9280..)  w2t : 9*32*4  fp32      (fallback conv2)
// [10432..) wB1 : 9*2*64*4 dwords   (conv1 MFMA B-fragments, bf16 pairs)
// [15040..) wB2 : 9*2*64*4 dwords   (conv2 MFMA B-fragments, hi/lo bf16 split, oc<4 valid)
// [19648..20288) red : RR*16 float2 partial sums (spread reduction slots)
// [20480..) rg   : RR*NN*hh*ww fp32 (log of pooled gt)
// [1556480..) pidx: RR*NN*hh*ww packed coords
// [3092480..) xb : NN*HH*WW*16 dwords (bf16 channel-pairs, channel-last)
#define WS_W1T 64
#define WS_W2T 9280
#define WS_WB1 10432
#define WS_WB2 15040
#define WS_RED 19648
#define WS_RG  20480
#define WS_IDX 1556480
#define WS_XB  3092480
#define XB_COUNT ((size_t)NN * HH * WW * 16)
#define WS_NEED_BYTES (((size_t)WS_XB + XB_COUNT) * 4)

// setup kernel block ranges
#define XPACK_B0 1
#define XPACK_NB (HH * NN)                 // 1920
#define POOL_B0  (XPACK_B0 + XPACK_NB)     // 1921
#define POOL_CB  (hh * ww / 256)           // 75 cell-blocks per (r,n)
#define POOL_NB  (POOL_CB * NN * RR)       // 6000
#define SETUP_NB (POOL_B0 + POOL_NB)       // 7921

typedef __attribute__((ext_vector_type(8))) short short8;
typedef __attribute__((ext_vector_type(4))) float f32x4;
typedef __attribute__((ext_vector_type(2))) float f32x2;

__device__ __forceinline__ unsigned int bf16pack(float a, float b) {
    unsigned int ua = __float_as_uint(a);
    ua = (ua + 0x7fffu + ((ua >> 16) & 1u)) >> 16;
    unsigned int ub = __float_as_uint(b);
    ub = (ub + 0x7fffu + ((ub >> 16) & 1u)) >> 16;
    return ua | (ub << 16);
}
__device__ __forceinline__ unsigned short bf16r(float f) {
    unsigned int u = __float_as_uint(f);
    u = (u + 0x7fffu + ((u >> 16) & 1u)) >> 16;
    return (unsigned short)u;
}
__device__ __forceinline__ float bf16tof(unsigned short s) {
    return __uint_as_float(((unsigned int)s) << 16);
}

// ---- merged setup: block 0 = weight prep, [1,1921) = xpack, [1921,7921) = pool ----
__global__ void setup_kernel(const float* __restrict__ x, const float* __restrict__ gts,
                             const float* __restrict__ rnd,
                             const float* __restrict__ W_att, const float* __restrict__ W_post,
                             float* __restrict__ ws) {
    const int b = blockIdx.x;
    const int tid = threadIdx.x;

    if (b == 0) {
        // ---- weight prep + zero reduction slots ----
        if (tid < 2*RR) ws[tid] = 0.f;
        for (int i = tid; i < RR*16*2; i += 256) ws[WS_RED + i] = 0.f;
        float* w1t = ws + WS_W1T;
        float* w2t = ws + WS_W2T;
        for (int i = tid; i < 32*32*9; i += 256) {
            int oc = i / (32*9); int rem = i % (32*9); int c = rem / 9; int tap = rem % 9;
            w1t[(tap*32 + c)*32 + oc] = W_att[i];
        }
        for (int i = tid; i < 4*32*9; i += 256) {
            int oc = i / (32*9); int rem = i % (32*9); int c = rem / 9; int tap = rem % 9;
            w2t[(tap*32 + c)*4 + oc] = W_post[i];
        }
        // conv1 MFMA B-fragments: B[k=c][n=oc] for 16x16x32 bf16.
        unsigned int* wb = (unsigned int*)(ws + WS_WB1);
        for (int i = tid; i < 9*2*64; i += 256) {
            int lane = i & 63; int th = i >> 6;
            int t = th >> 1, h2 = th & 1;
            int q = lane >> 4, col = lane & 15, oc = h2*16 + col;
            unsigned int vv[4];
            #pragma unroll
            for (int j = 0; j < 4; ++j) {
                int c0 = 8*q + 2*j;
                float f0 = W_att[(oc*32 + c0    )*9 + t];
                float f1 = W_att[(oc*32 + c0 + 1)*9 + t];
                vv[j] = bf16pack(f0, f1);
            }
            uint4 v4; v4.x = vv[0]; v4.y = vv[1]; v4.z = vv[2]; v4.w = vv[3];
            ((uint4*)wb)[i] = v4;
        }
        // conv2 MFMA B-fragments, hi/lo bf16 split; only oc<4 columns valid.
        unsigned int* wb2 = (unsigned int*)(ws + WS_WB2);
        for (int i = tid; i < 9*2*64; i += 256) {
            int lane = i & 63; int th = i >> 6;
            int t = th >> 1, part = th & 1;
            int q = lane >> 4, oc = lane & 15;
            unsigned int vv[4];
            #pragma unroll
            for (int j = 0; j < 4; ++j) {
                int c0 = 8*q + 2*j;
                float f0 = (oc < 4) ? W_post[(oc*32 + c0    )*9 + t] : 0.f;
                float f1 = (oc < 4) ? W_post[(oc*32 + c0 + 1)*9 + t] : 0.f;
                if (part == 0) {
                    vv[j] = ((unsigned int)bf16r(f0)) | (((unsigned int)bf16r(f1)) << 16);
                } else {
                    float l0 = f0 - bf16tof(bf16r(f0));
                    float l1 = f1 - bf16tof(bf16r(f1));
                    vv[j] = ((unsigned int)bf16r(l0)) | (((unsigned int)bf16r(l1)) << 16);
                }
            }
            uint4 v4; v4.x = vv[0]; v4.y = vv[1]; v4.z = vv[2]; v4.w = vv[3];
            ((uint4*)wb2)[i] = v4;
        }
    } else if (b < POOL_B0) {
        // ---- xpack: x[n][c][y][:] fp32 -> xb[n][y][x][cp] bf16-pair (64B/pixel) ----
        const int bb = b - XPACK_B0;
        const int y = bb % HH;
        const int n = bb / HH;
        unsigned int* xb = (unsigned int*)(ws + WS_XB);
        for (int px = tid; px < WW; px += 256) {
            unsigned int* o = xb + ((size_t)(n*HH + y)*WW + px) * 16;
            uint4 v[4];
            #pragma unroll
            for (int k = 0; k < 4; ++k) {
                #pragma unroll
                for (int j = 0; j < 4; ++j) {
                    int cp = 4*k + j;
                    float f0 = x[((size_t)(n*FC + 2*cp    )*HH + y)*WW + px];
                    float f1 = x[((size_t)(n*FC + 2*cp + 1)*HH + y)*WW + px];
                    ((unsigned int*)&v[k])[j] = bf16pack(f0, f1);
                }
            }
            #pragma unroll
            for (int k = 0; k < 4; ++k) ((uint4*)o)[k] = v[k];
        }
    } else {
        // ---- pool: one thread per (h,w) cell; store log(pooled gt) + packed coords ----
        const int bb = b - POOL_B0;
        const int r  = bb / (POOL_CB * NN);
        const int rem = bb % (POOL_CB * NN);
        const int n  = rem / POOL_CB;
        const int cb = rem % POOL_CB;
        const int cell = cb * 256 + tid;
        const int h = cell / ww, w = cell % ww;
        const float* gt_n = gts + (size_t)n * HH * WW;
        const float* rd_n = rnd + ((size_t)r * NN + n) * (size_t)(HH * WW);
        float best = -1.f, bg = 0.f; int bii = 0, bjj = 0;
        #pragma unroll
        for (int bi = 0; bi < 4; ++bi) {
            const float4 g4 = *(const float4*)(gt_n + (size_t)(h*4 + bi)*WW + w*4);
            const float4 r4 = *(const float4*)(rd_n + (size_t)(h*4 + bi)*WW + w*4);
            const float gv[4] = {g4.x, g4.y, g4.z, g4.w};
            const float rv[4] = {r4.x, r4.y, r4.z, r4.w};
            #pragma unroll
            for (int bj = 0; bj < 4; ++bj) {
                float rm = (gv[bj] > 0.1f) ? rv[bj] : 0.f;
                if (rm > best) { best = rm; bii = bi; bjj = bj; bg = gv[bj]; }
            }
        }
        int idx_b = (h*4 + bii) * WW + (w*4 + bjj) + BIAS_IDX;
        size_t o = ((size_t)(r*NN + n) * (hh*ww)) + cell;
        float g2 = (bg < 0.1f) ? 0.f : bg;
        ((float*)(ws + WS_RG))[o] = logf(g2 + 1e-6f);
        ((unsigned int*)(ws + WS_IDX))[o] = ((unsigned int)(idx_b / WW) << 16) | (unsigned int)(idx_b % WW);
    }
}

// s_feat chunk swizzle: pixel p's 16B chunk k lives at slot (k ^ ((p>>1)&3)).
// launch_bounds (256,4): 128-reg budget.  (256,5)=102 regs caused an ~8-dword/thread
// spill (r4: WRITE_SIZE 66 MB of scratch); (256,7)=73 was catastrophic (r3).
// Measured occupancy at (256,5) was already ~4 blocks/CU, so (256,4) costs nothing.
__launch_bounds__(256, 4)
__global__ void wvl_main(const unsigned int* __restrict__ xb, const float* __restrict__ d,
                         const float* __restrict__ b_att, const float* __restrict__ b_post,
                         float* __restrict__ ws) {
    // s_feat: phase A = feat, channel-last [pix][16] (FT*FT pixels, chunk-swizzled).
    // phase B (overlay) = att*d, channel-last [pix][16] (ATT*ATT pixels) -> conv2 A-frags.
    __shared__ unsigned int s_feat[FT * FT * 16];   // 5184 dwords = 20.7 KB
    __shared__ float s_plog[FT * FT];
    __shared__ float s_rn[4], s_rd[4];

    const float* lg_all  = (const float*)(ws + WS_RG);
    const unsigned int* pidx_all = (const unsigned int*)(ws + WS_IDX);

    const int tid = threadIdx.x;

    // ---- XCD-locality swizzle ----
    // 72 groups of 120 blocks, group = (n, ty, tx-half); group g pinned to XCD g%8,
    // 9 groups per XCD.  Each group's unique xb region ~1.7 MB -> L2-resident.
    const int f   = blockIdx.x;        // 0..8639
    const int xcd = f & 7;
    const int bb  = f >> 3;            // 0..1079 : slot within xcd
    const int gi  = bb / 120;          // group slot 0..8
    const int ii  = bb % 120;          // index within group
    const int band = gi * 8 + xcd;     // 0..71
    const int n   = band / 18;
    const int rem = band % 18;
    const int ty  = rem >> 1;
    const int tx  = (rem & 1) * 6 + (ii % 6);
    const int r   = ii / 6;

    const int py0 = ty * TILE - 2;
    const int px0 = tx * TILE - 2;

    const size_t pbase = (size_t)(r*NN + n) * (hh*ww);

    // ------- Stage 1: stage log-gt tile (18x18) into LDS -------
    for (int p = tid; p < FT * FT; p += 256) {
        int pi = p / FT, pj = p % FT;
        int gi2 = py0 + pi, gj = px0 + pj;
        float lval = LOGEPS;
        if (gi2 >= 0 && gi2 < hh && gj >= 0 && gj < ww)
            lval = lg_all[pbase + (size_t)gi2 * ww + gj];
        s_plog[p] = lval;
    }

    // ------- Stage 2: bilinear gather from packed bf16 x -> channel-last LDS -------
    for (int p = tid; p < FT * FT; p += 256) {
        int pi = p / FT, pj = p % FT;
        int gi2 = py0 + pi, gj = px0 + pj;
        unsigned int* dst = &s_feat[p * 16];
        const int sw = (p >> 1) & 3;
        if (gi2 < 0 || gi2 >= hh || gj < 0 || gj >= ww) {
            uint4 z; z.x = z.y = z.z = z.w = 0u;
            #pragma unroll
            for (int k = 0; k < 4; ++k) ((uint4*)dst)[k] = z;   // zeros: slot order moot
            continue;
        }
        unsigned int pk = pidx_all[pbase + (size_t)gi2 * ww + gj];
        int rr2 = (int)(pk >> 16);
        int cc  = (int)(pk & 0xffff);
        float gxf = 2.0f * ((float)cc  / (float)WW - 0.5f);
        float gyf = 2.0f * ((float)rr2 / (float)HH - 0.5f);
        float ix = (gxf + 1.0f) * 0.5f * (float)(WW - 1);
        float iy = (gyf + 1.0f) * 0.5f * (float)(HH - 1);
        float x0f = floorf(ix), y0f = floorf(iy);
        float wx = ix - x0f, wy = iy - y0f;
        int x0 = (int)x0f, y0 = (int)y0f;
        float vx0 = (x0f >= 0.f        && x0f <= (float)(WW-1)) ? 1.f : 0.f;
        float vx1 = (x0f + 1.f >= 0.f  && x0f + 1.f <= (float)(WW-1)) ? 1.f : 0.f;
        float vy0 = (y0f >= 0.f        && y0f <= (float)(HH-1)) ? 1.f : 0.f;
        float vy1 = (y0f + 1.f >= 0.f  && y0f + 1.f <= (float)(HH-1)) ? 1.f : 0.f;
        int xi0 = min(max(x0, 0), WW-1),  xi1 = min(max(x0+1, 0), WW-1);
        int yi0 = min(max(y0, 0), HH-1),  yi1 = min(max(y0+1, 0), HH-1);
        float w00 = (1.f-wx)*(1.f-wy) * (vx0*vy0);
        float w10 = wx*(1.f-wy)       * (vx1*vy0);
        float w01 = (1.f-wx)*wy       * (vx0*vy1);
        float w11 = wx*wy             * (vx1*vy1);
        const f32x2 vw00 = {w00, w00}, vw10 = {w10, w10}, vw01 = {w01, w01}, vw11 = {w11, w11};
        const uint4* q00 = (const uint4*)(xb + ((size_t)(n*HH + yi0)*WW + xi0) * 16);
        const uint4* q10 = (const uint4*)(xb + ((size_t)(n*HH + yi0)*WW + xi1) * 16);
        const uint4* q01 = (const uint4*)(xb + ((size_t)(n*HH + yi1)*WW + xi0) * 16);
        const uint4* q11 = (const uint4*)(xb + ((size_t)(n*HH + yi1)*WW + xi1) * 16);
        #pragma unroll
        for (int k = 0; k < 4; ++k) {
            uint4 A = q00[k], B = q10[k], C = q01[k], D = q11[k];
            uint4 o;
            #pragma unroll
            for (int j = 0; j < 4; ++j) {
                unsigned int ua = ((const unsigned int*)&A)[j];
                unsigned int ub = ((const unsigned int*)&B)[j];
                unsigned int uc = ((const unsigned int*)&C)[j];
                unsigned int ud = ((const unsigned int*)&D)[j];
                f32x2 va = {__uint_as_float(ua << 16), __uint_as_float(ua & 0xffff0000u)};
                f32x2 vb = {__uint_as_float(ub << 16), __uint_as_float(ub & 0xffff0000u)};
                f32x2 vc = {__uint_as_float(uc << 16), __uint_as_float(uc & 0xffff0000u)};
                f32x2 vd = {__uint_as_float(ud << 16), __uint_as_float(ud & 0xffff0000u)};
                f32x2 acc = vw00 * va;
                acc += vw10 * vb;
                acc += vw01 * vc;
                acc += vw11 * vd;
                ((unsigned int*)&o)[j] = bf16pack(acc.x, acc.y);
            }
            ((uint4*)dst)[k ^ sw] = o;
        }
    }
    __syncthreads();

    // ------- Stage 3: conv1 via MFMA 16x16x32 bf16 -------
    // wave wv handles att rows ay = wv*4 + rr. m = att col (lane&15), n = oc.
    const int lane = tid & 63;
    const int wv   = tid >> 6;
    const int mcol = lane & 15;
    const int q    = lane >> 4;

    f32x4 acc1[4][2];
    {
        float bb0 = b_att[mcol];
        float bb1 = b_att[mcol + 16];
        #pragma unroll
        for (int rr = 0; rr < 4; ++rr) {
            acc1[rr][0] = (f32x4){bb0, bb0, bb0, bb0};
            acc1[rr][1] = (f32x4){bb1, bb1, bb1, bb1};
        }
    }
    {
        const uint4* wB = (const uint4*)(ws + WS_WB1);
        #pragma unroll
        for (int t = 0; t < 9; ++t) {
            union { uint4 u; short8 s; } b0u, b1u;
            b0u.u = wB[(t*2 + 0)*64 + lane];
            b1u.u = wB[(t*2 + 1)*64 + lane];
            const int dy = t / 3, dx = t % 3;
            #pragma unroll
            for (int rr = 0; rr < 4; ++rr) {
                int ay = wv*4 + rr;
                int pix = (ay + dy) * FT + dx + mcol;
                union { uint4 u; short8 s; } a;
                a.u = *(const uint4*)&s_feat[pix * 16 + (q ^ ((pix >> 1) & 3)) * 4];
                acc1[rr][0] = __builtin_amdgcn_mfma_f32_16x16x32_bf16(a.s, b0u.s, acc1[rr][0], 0, 0, 0);
                acc1[rr][1] = __builtin_amdgcn_mfma_f32_16x16x32_bf16(a.s, b1u.s, acc1[rr][1], 0, 0, 0);
            }
        }
    }
    __syncthreads();   // all feat reads done; s_feat can be overlaid with att*d

    // ------- Stage 3b: sigmoid + *d, write att*d overlay (channel-last, pix-major) -------
    // conv1 D layout: oc = lane&15 (+16*h2), ax = 4*q + reg, row ay = wv*4+rr
    // overlay dword: pix*16 + ((oc>>3)^((pix>>1)&3))*4 + ((oc>>1)&3), half oc&1
    {
        unsigned short* attd16 = (unsigned short*)s_feat;
        #pragma unroll
        for (int rr = 0; rr < 4; ++rr) {
            int ay = wv*4 + rr;
            int gy = ty * TILE - 1 + ay;
            bool gyok = (gy >= 0 && gy < hh);
            #pragma unroll
            for (int h2 = 0; h2 < 2; ++h2) {
                int oc = mcol + 16*h2;
                const float* drow = d + ((size_t)(n*DC + oc) * hh + (gyok ? gy : 0)) * ww;
                #pragma unroll
                for (int reg = 0; reg < 4; ++reg) {
                    int ax = 4*q + reg;
                    int gx = tx * TILE - 1 + ax;
                    float av = __builtin_amdgcn_rcpf(1.f + __expf(-acc1[rr][h2][reg]));
                    float dv = (gyok && gx >= 0 && gx < ww) ? drow[gx] : 0.f;
                    int pix = ay * ATT + ax;
                    int dwi = pix * 16 + ((oc >> 3) ^ ((pix >> 1) & 3)) * 4 + ((oc >> 1) & 3);
                    attd16[dwi * 2 + (oc & 1)] = bf16r(av * dv);
                }
            }
        }
    }
    __syncthreads();

    // ------- Stage 4: conv2 via MFMA (N=4 valid cols, hi/lo weights) + smooth-L1 epilogue ----
    // wave wv owns output rows qy = wv*4+rr (valid qy<14).  A lane m = output col qx,
    // D: oc = lane&15 (valid <4), qx = 4*(lane>>4)+reg.
    float num_t = 0.f, den_t = 0.f;
    {
        const uint4* wB2 = (const uint4*)(ws + WS_WB2);
        const int qy0 = wv * 4;
        float bias2 = (mcol < 4) ? b_post[mcol] : 0.f;
        f32x4 acc2[4];
        #pragma unroll
        for (int rr = 0; rr < 4; ++rr) acc2[rr] = (f32x4){bias2, bias2, bias2, bias2};
        #pragma unroll
        for (int t = 0; t < 9; ++t) {
            union { uint4 u; short8 s; } bh, bl;
            bh.u = wB2[(t*2 + 0)*64 + lane];
            bl.u = wB2[(t*2 + 1)*64 + lane];
            const int dy = t / 3, dx = t % 3;
            #pragma unroll
            for (int rr = 0; rr < 4; ++rr) {
                if (qy0 + rr >= TILE) break;        // uniform per wave
                int pix = (qy0 + rr + dy) * ATT + (mcol + dx);  // cols 16,17 bleed -> masked rows
                union { uint4 u; short8 s; } a;
                a.u = *(const uint4*)&s_feat[pix * 16 + (q ^ ((pix >> 1) & 3)) * 4];
                acc2[rr] = __builtin_amdgcn_mfma_f32_16x16x32_bf16(a.s, bh.s, acc2[rr], 0, 0, 0);
                acc2[rr] = __builtin_amdgcn_mfma_f32_16x16x32_bf16(a.s, bl.s, acc2[rr], 0, 0, 0);
            }
        }
        // epilogue: lane computes its (qx, oc) contribution; neighbor offset is f(oc)
        const int o3 = mcol & 3;
        const int oy = (o3 == 0) ? 0 : 1;
        const int ox = (o3 == 3) ? -1 : ((o3 == 2) ? 0 : 1);
        #pragma unroll
        for (int rr = 0; rr < 4; ++rr) {
            if (qy0 + rr >= TILE) break;
            int qy = qy0 + rr;
            int gy2 = ty * TILE + qy;
            bool rowok = (gy2 < hh);
            #pragma unroll
            for (int reg = 0; reg < 4; ++reg) {
                int qx = 4*q + reg;
                int gx2 = tx * TILE + qx;
                float lc = s_plog[(qy + 2) * FT + (qx + 2)];
                float ln = s_plog[(qy + 2 + oy) * FT + (qx + 2 + ox)];
                bool m = rowok && (qx < TILE) && (gx2 < ww) && (mcol < 4)
                       && (lc > MTHR) && (ln > MTHR);
                float a2 = fabsf(acc2[rr][reg] - (lc - ln));
                float sl1 = (a2 < 0.01f) ? (50.f * a2 * a2) : (a2 - 0.005f);
                if (m) { num_t += sl1; den_t += 1.f; }
            }
        }
    }

    for (int off = 32; off > 0; off >>= 1) {
        num_t += __shfl_down(num_t, off);
        den_t += __shfl_down(den_t, off);
    }
    if (lane == 0) { s_rn[wv] = num_t; s_rd[wv] = den_t; }
    __syncthreads();
    if (tid == 0) {
        // spread reduction: 16 slots per r (float2 each) -> ~27 blocks share a slot,
        // ~430 RMWs per 64B line instead of 6912 (the r0-r4 ~290us atomic floor).
        int slot = r * 16 + (bb & 15);
        atomicAdd(&ws[WS_RED + slot*2],     s_rn[0] + s_rn[1] + s_rn[2] + s_rn[3]);
        atomicAdd(&ws[WS_RED + slot*2 + 1], s_rd[0] + s_rd[1] + s_rd[2] + s_rd[3]);
    }
}

// ---------------- fallback (used if ws too small) ----------------
__launch_bounds__(256, 6)
__global__ void wvl_fallback(const float* __restrict__ x, const float* __restrict__ d,
                             const float* __restrict__ gts, const float* __restrict__ rnd,
                             const float* __restrict__ b_att, const float* __restrict__ b_post,
                             float* __restrict__ ws) {
    __shared__ unsigned int s_buf[CP * FT * FT];
    __shared__ float s_pgt[FT * FT];
    __shared__ int   s_pidx[FT * FT];
    __shared__ float s_rn[4], s_rd[4];

    const float* w1t = ws + WS_W1T;
    const float* w2t = ws + WS_W2T;

    const int tid = threadIdx.x;
    const int tilesx = (ww + TILE - 1) / TILE;
    const int tx = blockIdx.x % tilesx;
    const int ty = blockIdx.x / tilesx;
    const int n  = blockIdx.y;
    const int r  = blockIdx.z;
    const int py0 = ty * TILE - 2;
    const int px0 = tx * TILE - 2;

    const float* gt_n = gts + (size_t)n * HH * WW;
    const float* rd_n = rnd + ((size_t)r * NN + n) * (size_t)(HH * WW);
    for (int p = tid; p < FT * FT; p += 256) {
        int pi = p / FT, pj = p % FT;
        int gi = py0 + pi, gj = px0 + pj;
        float gval = 0.f; int idx = -1;
        if (gi >= 0 && gi < hh && gj >= 0 && gj < ww) {
            float best = -1.f; int bii = 0, bjj = 0; float bg = 0.f;
            #pragma unroll
            for (int bi = 0; bi < 4; ++bi) {
                const float* gr = gt_n + (size_t)(gi*4 + bi) * WW + gj*4;
                const float* rp = rd_n + (size_t)(gi*4 + bi) * WW + gj*4;
                #pragma unroll
                for (int bj = 0; bj < 4; ++bj) {
                    float g  = gr[bj];
                    float rv = rp[bj];
                    float rm = (g > 0.1f) ? rv : 0.f;
                    if (rm > best) { best = rm; bii = bi; bjj = bj; bg = g; }
                }
            }
            gval = bg;
            idx = (gi*4 + bii) * WW + (gj*4 + bjj) + BIAS_IDX;
        }
        s_pgt[p]  = gval;
        s_pidx[p] = idx;
    }
    __syncthreads();

    const float* x_n = x + (size_t)n * FC * HH * WW;
    for (int p = tid; p < FT * FT; p += 256) {
        int idx = s_pidx[p];
        if (idx < 0) {
            #pragma unroll
            for (int cp = 0; cp < CP; ++cp) s_buf[cp * (FT*FT) + p] = 0u;
            continue;
        }
        int cc = idx % WW;
        int rr2 = idx / WW;
        float gxf = 2.0f * ((float)cc  / (float)WW - 0.5f);
        float gyf = 2.0f * ((float)rr2 / (float)HH - 0.5f);
        float ix = (gxf + 1.0f) * 0.5f * (float)(WW - 1);
        float iy = (gyf + 1.0f) * 0.5f * (float)(HH - 1);
        float x0f = floorf(ix), y0f = floorf(iy);
        float wx = ix - x0f, wy = iy - y0f;
        int x0 = (int)x0f, y0 = (int)y0f;
        float vx0 = (x0f >= 0.f        && x0f <= (float)(WW-1)) ? 1.f : 0.f;
        float vx1 = (x0f + 1.f >= 0.f  && x0f + 1.f <= (float)(WW-1)) ? 1.f : 0.f;
        float vy0 = (y0f >= 0.f        && y0f <= (float)(HH-1)) ? 1.f : 0.f;
        float vy1 = (y0f + 1.f >= 0.f  && y0f + 1.f <= (float)(HH-1)) ? 1.f : 0.f;
        int xi0 = min(max(x0, 0), WW-1),  xi1 = min(max(x0+1, 0), WW-1);
        int yi0 = min(max(y0, 0), HH-1),  yi1 = min(max(y0+1, 0), HH-1);
        float w00 = (1.f-wx)*(1.f-wy) * (vx0*vy0);
        float w10 = wx*(1.f-wy)       * (vx1*vy0);
        float w01 = (1.f-wx)*wy       * (vx0*vy1);
        float w11 = wx*wy             * (vx1*vy1);
        const float* p00 = x_n + (size_t)yi0 * WW + xi0;
        const float* p10 = x_n + (size_t)yi0 * WW + xi1;
        const float* p01 = x_n + (size_t)yi1 * WW + xi0;
        const float* p11 = x_n + (size_t)yi1 * WW + xi1;
        #pragma unroll 4
        for (int cp = 0; cp < CP; ++cp) {
            int o0 = (2*cp)     * (HH * WW);
            int o1 = (2*cp + 1) * (HH * WW);
            float f0 = w00 * p00[o0] + w10 * p10[o0] + w01 * p01[o0] + w11 * p11[o0];
            float f1 = w00 * p00[o1] + w10 * p10[o1] + w01 * p01[o1] + w11 * p11[o1];
            s_buf[cp * (FT*FT) + p] = bf16pack(f0, f1);
        }
    }
    __syncthreads();

    const int ay = tid >> 4, ax = tid & 15;
    float acc[32];
    #pragma unroll
    for (int oc = 0; oc < 32; ++oc) acc[oc] = b_att[oc];
    for (int dy = 0; dy < 3; ++dy) {
        for (int dx = 0; dx < 3; ++dx) {
            const float* wt = w1t + (dy*3 + dx) * 1024;
            int base = (ay + dy) * FT + (ax + dx);
            for (int cp = 0; cp < CP; ++cp) {
                unsigned int u = s_buf[cp * (FT*FT) + base];
                float f0 = __uint_as_float(u << 16);
                float f1 = __uint_as_float(u & 0xffff0000u);
                const float* wp0 = wt + (2*cp) * 32;
                const float* wp1 = wp0 + 32;
                #pragma unroll
                for (int oc = 0; oc < 32; ++oc) acc[oc] = fmaf(f0, wp0[oc], acc[oc]);
                #pragma unroll
                for (int oc = 0; oc < 32; ++oc) acc[oc] = fmaf(f1, wp1[oc], acc[oc]);
            }
        }
    }
    __syncthreads();
    {
        int gy = ty * TILE - 1 + ay;
        int gx = tx * TILE - 1 + ax;
        bool inb = (gy >= 0 && gy < hh && gx >= 0 && gx < ww);
        const float* d_n = d + (size_t)n * DC * hh * ww;
        #pragma unroll
        for (int cp = 0; cp < CP; ++cp) {
            float a0 = 1.f / (1.f + __expf(-acc[2*cp]));
            float a1 = 1.f / (1.f + __expf(-acc[2*cp+1]));
            float v0 = 0.f, v1 = 0.f;
            if (inb) {
                v0 = a0 * d_n[(size_t)((2*cp)   * hh + gy) * ww + gx];
                v1 = a1 * d_n[(size_t)((2*cp+1) * hh + gy) * ww + gx];
            }
            s_buf[cp * (ATT*ATT) + tid] = bf16pack(v0, v1);
        }
    }
    __syncthreads();

    float num_t = 0.f, den_t = 0.f;
    if (tid < TILE * TILE) {
        int qy = tid / TILE, qx = tid % TILE;
        int gy2 = ty * TILE + qy, gx2 = tx * TILE + qx;
        if (gy2 < hh && gx2 < ww) {
            float acc2[4];
            #pragma unroll
            for (int k = 0; k < 4; ++k) acc2[k] = b_post[k];
            for (int dy = 0; dy < 3; ++dy) {
                for (int dx = 0; dx < 3; ++dx) {
                    const float* wt = w2t + (dy*3 + dx) * 128;
                    int base = (qy + dy) * ATT + (qx + dx);
                    for (int cp = 0; cp < CP; ++cp) {
                        unsigned int u = s_buf[cp * (ATT*ATT) + base];
                        float f0 = __uint_as_float(u << 16);
                        float f1 = __uint_as_float(u & 0xffff0000u);
                        const float* wp0 = wt + (2*cp) * 4;
                        const float* wp1 = wp0 + 4;
                        #pragma unroll
                        for (int k2 = 0; k2 < 4; ++k2) acc2[k2] = fmaf(f0, wp0[k2], acc2[k2]);
                        #pragma unroll
                        for (int k2 = 0; k2 < 4; ++k2) acc2[k2] = fmaf(f1, wp1[k2], acc2[k2]);
                    }
                }
            }
            int pc = (qy + 2) * FT + (qx + 2);
            float rgc = s_pgt[pc]; rgc = (rgc < 0.1f) ? 0.f : rgc;
            float lc = logf(rgc + 1e-6f);
            bool  mc = rgc > 0.1f;
            const int oys[4] = {0, 1, 1, 1};
            const int oxs[4] = {1, 1, 0, -1};
            #pragma unroll
            for (int k = 0; k < 4; ++k) {
                int pnb = (qy + 2 + oys[k]) * FT + (qx + 2 + oxs[k]);
                float rgn = s_pgt[pnb]; rgn = (rgn < 0.1f) ? 0.f : rgn;
                float ln = logf(rgn + 1e-6f);
                bool m = mc && (rgn > 0.1f);
                float gg = lc - ln;
                float a2 = fabsf(acc2[k] - gg);
                float sl1 = (a2 < 0.01f) ? (0.5f * a2 * a2 / 0.01f) : (a2 - 0.005f);
                if (m) { num_t += sl1; den_t += 1.f; }
            }
        }
    }
    for (int off = 32; off > 0; off >>= 1) {
        num_t += __shfl_down(num_t, off);
        den_t += __shfl_down(den_t, off);
    }
    int wid = tid >> 6, lane = tid & 63;
    if (lane == 0) { s_rn[wid] = num_t; s_rd[wid] = den_t; }
    __syncthreads();
    if (tid == 0) {
        int slot = r * 16 + (blockIdx.x & 15);
        atomicAdd(&ws[WS_RED + slot*2],     s_rn[0] + s_rn[1] + s_rn[2] + s_rn[3]);
        atomicAdd(&ws[WS_RED + slot*2 + 1], s_rd[0] + s_rd[1] + s_rd[2] + s_rd[3]);
    }
}

// reduce the RR*16 float2 slots -> loss
__global__ void finish_kernel(const float* __restrict__ ws, float* __restrict__ out) {
    __shared__ float sn[RR], sd[RR];
    const int tid = threadIdx.x;
    if (tid < RR) { sn[tid] = 0.f; sd[tid] = 0.f; }
    __syncthreads();
    if (tid < RR * 16) {
        int r2 = tid >> 4;
        atomicAdd(&sn[r2], ws[WS_RED + tid*2]);
        atomicAdd(&sd[r2], ws[WS_RED + tid*2 + 1]);
    }
    __syncthreads();
    if (tid == 0) {
        float s = 0.f;
        for (int r2 = 0; r2 < RR; ++r2) s += sn[r2] / sd[r2];
        out[0] = s / (float)RR;
    }
}

extern "C" void kernel_launch(void* const* d_in, const int* in_sizes, int n_in,
                              void* d_out, int out_size, void* d_ws, size_t ws_size,
                              hipStream_t stream) {
    const float* x      = (const float*)d_in[0];
    const float* d      = (const float*)d_in[1];
    const float* gts    = (const float*)d_in[2];
    const float* rnd    = (const float*)d_in[3];
    const float* W_att  = (const float*)d_in[4];
    const float* b_att  = (const float*)d_in[5];
    const float* W_post = (const float*)d_in[6];
    const float* b_post = (const float*)d_in[7];
    float* out = (float*)d_out;
    float* ws  = (float*)d_ws;

    const int tilesx = (ww + TILE - 1) / TILE;  // 12
    const int tilesy = (hh + TILE - 1) / TILE;  // 9

    if (ws_size >= WS_NEED_BYTES) {
        hipLaunchKernelGGL(setup_kernel, dim3(SETUP_NB), dim3(256), 0, stream,
                           x, gts, rnd, W_att, W_post, ws);
        unsigned int* xb = (unsigned int*)(ws + WS_XB);
        // 1-D swizzled grid: 72 groups x 120 blocks = 8640 = tilesx*tilesy*NN*RR
        hipLaunchKernelGGL(wvl_main, dim3(tilesx * tilesy * NN * RR), dim3(256), 0, stream,
                           xb, d, b_att, b_post, ws);
    } else {
        hipLaunchKernelGGL(setup_kernel, dim3(1), dim3(256), 0, stream,
                           x, gts, rnd, W_att, W_post, ws);   // block 0 = weight prep only
        dim3 grid2(tilesx * tilesy, NN, RR);
        hipLaunchKernelGGL(wvl_fallback, grid2, dim3(256), 0, stream,
                           x, d, gts, rnd, b_att, b_post, ws);
    }

    hipLaunchKernelGGL(finish_kernel, dim3(1), dim3(512), 0, stream, ws, out);
}

// Round 6
// 498.464 us; speedup vs baseline: 1.7213x; 1.1655x over previous
//
#include <hip/hip_runtime.h>
#include <math.h>

#define NN 4
#define FC 32
#define DC 32
#define HH 480
#define WW 640
#define hh 120
#define ww 160
#define RR 20
#define TILE 14
#define ATT 16   // TILE+2 : conv1 output region (att pixels)
#define FT 18    // TILE+4 : feat / pooling region
#define BIAS_IDX 1282  // W//w//2 + (H//h//2)*W = 2 + 2*640
#define CP 16    // channel pairs (32 channels / 2)
#define LOGEPS -13.815511f   // log(1e-6)
#define MTHR   -8.0f         // mask threshold: valid logs are > -2.31, zeros are -13.8

// workspace layout (dword units):
// [0..40)   legacy num/den (unused by main path)
// [64..)    w1t : 9*32*32 fp32      (fallback conv1)
// [9280..)  w2t : 9*32*4  fp32      (fallback conv2)
// [10432..) wB1 : 9*2*64*4 dwords   (conv1 MFMA weight fragments, bf16 pairs)
// [15040..) wB2 : 9*2*64*4 dwords   (conv2 MFMA weight fragments, hi/lo bf16 split, oc<4 valid)
// [19648..20288) red : RR*16 float2 partial sums (spread reduction slots)
// [20480..) rg   : RR*NN*hh*ww fp32 (log of pooled gt)
// [1556480..) pidx: RR*NN*hh*ww packed coords
// [3092480..) xb : NN*HH*WW*16 dwords (bf16 channel-pairs, channel-last)
// [22753280..) dpk: NN*hh*ww*32 fp32 (d channel-last)
#define WS_W1T 64
#define WS_W2T 9280
#define WS_WB1 10432
#define WS_WB2 15040
#define WS_RED 19648
#define WS_RG  20480
#define WS_IDX 1556480
#define WS_XB  3092480
#define XB_COUNT ((size_t)NN * HH * WW * 16)
#define WS_DPK (WS_XB + 19660800)          // 22753280
#define DPK_COUNT ((size_t)NN * hh * ww * 32)
#define WS_NEED_BYTES (((size_t)WS_DPK + DPK_COUNT) * 4)

// setup kernel block ranges
#define XPACK_B0 1
#define XPACK_NB (HH * NN)                 // 1920
#define POOL_B0  (XPACK_B0 + XPACK_NB)     // 1921
#define POOL_CB  (hh * ww / 256)           // 75 cell-blocks per (r,n)
#define POOL_NB  (POOL_CB * NN * RR)       // 6000
#define DPK_B0   (POOL_B0 + POOL_NB)       // 7921
#define DPK_NB   (NN * hh)                 // 480
#define SETUP_NB (DPK_B0 + DPK_NB)         // 8401

typedef __attribute__((ext_vector_type(8))) short short8;
typedef __attribute__((ext_vector_type(4))) float f32x4;
typedef __attribute__((ext_vector_type(2))) float f32x2;

__device__ __forceinline__ unsigned int bf16pack(float a, float b) {
    unsigned int ua = __float_as_uint(a);
    ua = (ua + 0x7fffu + ((ua >> 16) & 1u)) >> 16;
    unsigned int ub = __float_as_uint(b);
    ub = (ub + 0x7fffu + ((ub >> 16) & 1u)) >> 16;
    return ua | (ub << 16);
}
__device__ __forceinline__ unsigned short bf16r(float f) {
    unsigned int u = __float_as_uint(f);
    u = (u + 0x7fffu + ((u >> 16) & 1u)) >> 16;
    return (unsigned short)u;
}
__device__ __forceinline__ float bf16tof(unsigned short s) {
    return __uint_as_float(((unsigned int)s) << 16);
}

// ---- merged setup: block 0 = weights, [1,1921) xpack, [1921,7921) pool, [7921,8401) dpack ----
__global__ void setup_kernel(const float* __restrict__ x, const float* __restrict__ d,
                             const float* __restrict__ gts, const float* __restrict__ rnd,
                             const float* __restrict__ W_att, const float* __restrict__ W_post,
                             float* __restrict__ ws) {
    const int b = blockIdx.x;
    const int tid = threadIdx.x;

    if (b == 0) {
        // ---- weight prep + zero reduction slots ----
        if (tid < 2*RR) ws[tid] = 0.f;
        for (int i = tid; i < RR*16*2; i += 256) ws[WS_RED + i] = 0.f;
        float* w1t = ws + WS_W1T;
        float* w2t = ws + WS_W2T;
        for (int i = tid; i < 32*32*9; i += 256) {
            int oc = i / (32*9); int rem = i % (32*9); int c = rem / 9; int tap = rem % 9;
            w1t[(tap*32 + c)*32 + oc] = W_att[i];
        }
        for (int i = tid; i < 4*32*9; i += 256) {
            int oc = i / (32*9); int rem = i % (32*9); int c = rem / 9; int tap = rem % 9;
            w2t[(tap*32 + c)*4 + oc] = W_post[i];
        }
        // conv1 MFMA weight fragments: free index = oc (lane&15), k-slice 8*(lane>>4)+j.
        // Layout identical for A- and B-operand use (16x16x32 frag symmetry).
        unsigned int* wb = (unsigned int*)(ws + WS_WB1);
        for (int i = tid; i < 9*2*64; i += 256) {
            int lane = i & 63; int th = i >> 6;
            int t = th >> 1, h2 = th & 1;
            int q = lane >> 4, col = lane & 15, oc = h2*16 + col;
            unsigned int vv[4];
            #pragma unroll
            for (int j = 0; j < 4; ++j) {
                int c0 = 8*q + 2*j;
                float f0 = W_att[(oc*32 + c0    )*9 + t];
                float f1 = W_att[(oc*32 + c0 + 1)*9 + t];
                vv[j] = bf16pack(f0, f1);
            }
            uint4 v4; v4.x = vv[0]; v4.y = vv[1]; v4.z = vv[2]; v4.w = vv[3];
            ((uint4*)wb)[i] = v4;
        }
        // conv2 MFMA weight fragments, hi/lo bf16 split; only oc<4 columns valid.
        unsigned int* wb2 = (unsigned int*)(ws + WS_WB2);
        for (int i = tid; i < 9*2*64; i += 256) {
            int lane = i & 63; int th = i >> 6;
            int t = th >> 1, part = th & 1;
            int q = lane >> 4, oc = lane & 15;
            unsigned int vv[4];
            #pragma unroll
            for (int j = 0; j < 4; ++j) {
                int c0 = 8*q + 2*j;
                float f0 = (oc < 4) ? W_post[(oc*32 + c0    )*9 + t] : 0.f;
                float f1 = (oc < 4) ? W_post[(oc*32 + c0 + 1)*9 + t] : 0.f;
                if (part == 0) {
                    vv[j] = ((unsigned int)bf16r(f0)) | (((unsigned int)bf16r(f1)) << 16);
                } else {
                    float l0 = f0 - bf16tof(bf16r(f0));
                    float l1 = f1 - bf16tof(bf16r(f1));
                    vv[j] = ((unsigned int)bf16r(l0)) | (((unsigned int)bf16r(l1)) << 16);
                }
            }
            uint4 v4; v4.x = vv[0]; v4.y = vv[1]; v4.z = vv[2]; v4.w = vv[3];
            ((uint4*)wb2)[i] = v4;
        }
    } else if (b < POOL_B0) {
        // ---- xpack: x[n][c][y][:] fp32 -> xb[n][y][x][cp] bf16-pair (64B/pixel) ----
        const int bb = b - XPACK_B0;
        const int y = bb % HH;
        const int n = bb / HH;
        unsigned int* xb = (unsigned int*)(ws + WS_XB);
        for (int px = tid; px < WW; px += 256) {
            unsigned int* o = xb + ((size_t)(n*HH + y)*WW + px) * 16;
            uint4 v[4];
            #pragma unroll
            for (int k = 0; k < 4; ++k) {
                #pragma unroll
                for (int j = 0; j < 4; ++j) {
                    int cp = 4*k + j;
                    float f0 = x[((size_t)(n*FC + 2*cp    )*HH + y)*WW + px];
                    float f1 = x[((size_t)(n*FC + 2*cp + 1)*HH + y)*WW + px];
                    ((unsigned int*)&v[k])[j] = bf16pack(f0, f1);
                }
            }
            #pragma unroll
            for (int k = 0; k < 4; ++k) ((uint4*)o)[k] = v[k];
        }
    } else if (b < DPK_B0) {
        // ---- pool: one thread per (h,w) cell; store log(pooled gt) + packed coords ----
        const int bb = b - POOL_B0;
        const int r  = bb / (POOL_CB * NN);
        const int rem = bb % (POOL_CB * NN);
        const int n  = rem / POOL_CB;
        const int cb = rem % POOL_CB;
        const int cell = cb * 256 + tid;
        const int h = cell / ww, w = cell % ww;
        const float* gt_n = gts + (size_t)n * HH * WW;
        const float* rd_n = rnd + ((size_t)r * NN + n) * (size_t)(HH * WW);
        float best = -1.f, bg = 0.f; int bii = 0, bjj = 0;
        #pragma unroll
        for (int bi = 0; bi < 4; ++bi) {
            const float4 g4 = *(const float4*)(gt_n + (size_t)(h*4 + bi)*WW + w*4);
            const float4 r4 = *(const float4*)(rd_n + (size_t)(h*4 + bi)*WW + w*4);
            const float gv[4] = {g4.x, g4.y, g4.z, g4.w};
            const float rv[4] = {r4.x, r4.y, r4.z, r4.w};
            #pragma unroll
            for (int bj = 0; bj < 4; ++bj) {
                float rm = (gv[bj] > 0.1f) ? rv[bj] : 0.f;
                if (rm > best) { best = rm; bii = bi; bjj = bj; bg = gv[bj]; }
            }
        }
        int idx_b = (h*4 + bii) * WW + (w*4 + bjj) + BIAS_IDX;
        size_t o = ((size_t)(r*NN + n) * (hh*ww)) + cell;
        float g2 = (bg < 0.1f) ? 0.f : bg;
        ((float*)(ws + WS_RG))[o] = logf(g2 + 1e-6f);
        ((unsigned int*)(ws + WS_IDX))[o] = ((unsigned int)(idx_b / WW) << 16) | (unsigned int)(idx_b % WW);
    } else {
        // ---- dpack: d[n][c][y][x] fp32 -> dpk[n][y][x][c] fp32 (128B/pixel) ----
        const int bb = b - DPK_B0;
        const int n = bb / hh;
        const int y = bb % hh;
        float* dpk = ws + WS_DPK;
        if (tid < ww) {
            int px = tid;
            float v[32];
            #pragma unroll
            for (int c = 0; c < 32; ++c)
                v[c] = d[((size_t)(n*DC + c) * hh + y) * ww + px];
            float* o = dpk + ((size_t)(n*hh + y)*ww + px) * 32;
            #pragma unroll
            for (int k = 0; k < 8; ++k)
                ((float4*)o)[k] = *(const float4*)&v[4*k];
        }
    }
}

// s_feat chunk swizzle: pixel p's 16B chunk k lives at slot (k ^ ((p>>1)&3)).
// launch_bounds (256,4): 128-reg budget.  (256,5)=102 regs spilled (r4: +66 MB
// scratch WRITE); (256,7)=73 catastrophic (r3).  Do not raise past 4.
// MFMA operand order: mfma(WEIGHTS, DATA) -> D: col = pixel (lane&15), row = oc
// (4*(lane>>4)+reg).  A/B fragments have identical lane layouts, so the LDS and
// weight reads are unchanged vs the data-first form; only D interpretation flips.
// This makes each lane own ONE pixel and 8 consecutive oc -> contiguous dpk loads
// (2x float4) and packed overlay writes (2x b64) in stage 3b.
__launch_bounds__(256, 4)
__global__ void wvl_main(const unsigned int* __restrict__ xb,
                         const float* __restrict__ b_att, const float* __restrict__ b_post,
                         float* __restrict__ ws) {
    // s_feat: phase A = feat, channel-last [pix][16] (FT*FT pixels, chunk-swizzled).
    // phase B (overlay) = att*d, channel-last [pix][16] (ATT*ATT pixels) -> conv2 frags.
    __shared__ unsigned int s_feat[FT * FT * 16];   // 5184 dwords = 20.7 KB
    __shared__ float s_plog[FT * FT];
    __shared__ float s_rn[4], s_rd[4];

    const float* lg_all  = (const float*)(ws + WS_RG);
    const unsigned int* pidx_all = (const unsigned int*)(ws + WS_IDX);

    const int tid = threadIdx.x;

    // ---- XCD-locality swizzle ----
    // 72 groups of 120 blocks, group = (n, ty, tx-half); group g pinned to XCD g%8,
    // 9 groups per XCD.  Each group's unique xb region ~1.7 MB -> L2-resident.
    const int f   = blockIdx.x;        // 0..8639
    const int xcd = f & 7;
    const int bb  = f >> 3;            // 0..1079 : slot within xcd
    const int gi  = bb / 120;          // group slot 0..8
    const int ii  = bb % 120;          // index within group
    const int band = gi * 8 + xcd;     // 0..71
    const int n   = band / 18;
    const int rem = band % 18;
    const int ty  = rem >> 1;
    const int tx  = (rem & 1) * 6 + (ii % 6);
    const int r   = ii / 6;

    const int py0 = ty * TILE - 2;
    const int px0 = tx * TILE - 2;

    const size_t pbase = (size_t)(r*NN + n) * (hh*ww);

    // ------- Stage 1: stage log-gt tile (18x18) into LDS -------
    for (int p = tid; p < FT * FT; p += 256) {
        int pi = p / FT, pj = p % FT;
        int gi2 = py0 + pi, gj = px0 + pj;
        float lval = LOGEPS;
        if (gi2 >= 0 && gi2 < hh && gj >= 0 && gj < ww)
            lval = lg_all[pbase + (size_t)gi2 * ww + gj];
        s_plog[p] = lval;
    }

    // ------- Stage 2: bilinear gather from packed bf16 x -> channel-last LDS -------
    for (int p = tid; p < FT * FT; p += 256) {
        int pi = p / FT, pj = p % FT;
        int gi2 = py0 + pi, gj = px0 + pj;
        unsigned int* dst = &s_feat[p * 16];
        const int sw = (p >> 1) & 3;
        if (gi2 < 0 || gi2 >= hh || gj < 0 || gj >= ww) {
            uint4 z; z.x = z.y = z.z = z.w = 0u;
            #pragma unroll
            for (int k = 0; k < 4; ++k) ((uint4*)dst)[k] = z;   // zeros: slot order moot
            continue;
        }
        unsigned int pk = pidx_all[pbase + (size_t)gi2 * ww + gj];
        int rr2 = (int)(pk >> 16);
        int cc  = (int)(pk & 0xffff);
        float gxf = 2.0f * ((float)cc  / (float)WW - 0.5f);
        float gyf = 2.0f * ((float)rr2 / (float)HH - 0.5f);
        float ix = (gxf + 1.0f) * 0.5f * (float)(WW - 1);
        float iy = (gyf + 1.0f) * 0.5f * (float)(HH - 1);
        float x0f = floorf(ix), y0f = floorf(iy);
        float wx = ix - x0f, wy = iy - y0f;
        int x0 = (int)x0f, y0 = (int)y0f;
        float vx0 = (x0f >= 0.f        && x0f <= (float)(WW-1)) ? 1.f : 0.f;
        float vx1 = (x0f + 1.f >= 0.f  && x0f + 1.f <= (float)(WW-1)) ? 1.f : 0.f;
        float vy0 = (y0f >= 0.f        && y0f <= (float)(HH-1)) ? 1.f : 0.f;
        float vy1 = (y0f + 1.f >= 0.f  && y0f + 1.f <= (float)(HH-1)) ? 1.f : 0.f;
        int xi0 = min(max(x0, 0), WW-1),  xi1 = min(max(x0+1, 0), WW-1);
        int yi0 = min(max(y0, 0), HH-1),  yi1 = min(max(y0+1, 0), HH-1);
        float w00 = (1.f-wx)*(1.f-wy) * (vx0*vy0);
        float w10 = wx*(1.f-wy)       * (vx1*vy0);
        float w01 = (1.f-wx)*wy       * (vx0*vy1);
        float w11 = wx*wy             * (vx1*vy1);
        const f32x2 vw00 = {w00, w00}, vw10 = {w10, w10}, vw01 = {w01, w01}, vw11 = {w11, w11};
        const uint4* q00 = (const uint4*)(xb + ((size_t)(n*HH + yi0)*WW + xi0) * 16);
        const uint4* q10 = (const uint4*)(xb + ((size_t)(n*HH + yi0)*WW + xi1) * 16);
        const uint4* q01 = (const uint4*)(xb + ((size_t)(n*HH + yi1)*WW + xi0) * 16);
        const uint4* q11 = (const uint4*)(xb + ((size_t)(n*HH + yi1)*WW + xi1) * 16);
        #pragma unroll
        for (int k = 0; k < 4; ++k) {
            uint4 A = q00[k], B = q10[k], C = q01[k], D = q11[k];
            uint4 o;
            #pragma unroll
            for (int j = 0; j < 4; ++j) {
                unsigned int ua = ((const unsigned int*)&A)[j];
                unsigned int ub = ((const unsigned int*)&B)[j];
                unsigned int uc = ((const unsigned int*)&C)[j];
                unsigned int ud = ((const unsigned int*)&D)[j];
                f32x2 va = {__uint_as_float(ua << 16), __uint_as_float(ua & 0xffff0000u)};
                f32x2 vb = {__uint_as_float(ub << 16), __uint_as_float(ub & 0xffff0000u)};
                f32x2 vc = {__uint_as_float(uc << 16), __uint_as_float(uc & 0xffff0000u)};
                f32x2 vd = {__uint_as_float(ud << 16), __uint_as_float(ud & 0xffff0000u)};
                f32x2 acc = vw00 * va;
                acc += vw10 * vb;
                acc += vw01 * vc;
                acc += vw11 * vd;
                ((unsigned int*)&o)[j] = bf16pack(acc.x, acc.y);
            }
            ((uint4*)dst)[k ^ sw] = o;
        }
    }
    __syncthreads();

    // ------- Stage 3: conv1 via MFMA (weights-first) -------
    // wave wv handles att rows ay = wv*4 + rr.  D: pixel = mcol, oc = 16*h + 4q+reg.
    const int lane = tid & 63;
    const int wv   = tid >> 6;
    const int mcol = lane & 15;
    const int q    = lane >> 4;

    f32x4 acc1[4][2];
    {
        const f32x4 bv0 = ((const f32x4*)b_att)[q];      // b_att[4q..4q+3]
        const f32x4 bv1 = ((const f32x4*)b_att)[4 + q];  // b_att[16+4q..]
        #pragma unroll
        for (int rr = 0; rr < 4; ++rr) {
            acc1[rr][0] = bv0;
            acc1[rr][1] = bv1;
        }
    }
    {
        const uint4* wB = (const uint4*)(ws + WS_WB1);
        #pragma unroll
        for (int t = 0; t < 9; ++t) {
            union { uint4 u; short8 s; } b0u, b1u;
            b0u.u = wB[(t*2 + 0)*64 + lane];
            b1u.u = wB[(t*2 + 1)*64 + lane];
            const int dy = t / 3, dx = t % 3;
            #pragma unroll
            for (int rr = 0; rr < 4; ++rr) {
                int ay = wv*4 + rr;
                int pix = (ay + dy) * FT + dx + mcol;
                union { uint4 u; short8 s; } a;
                a.u = *(const uint4*)&s_feat[pix * 16 + (q ^ ((pix >> 1) & 3)) * 4];
                acc1[rr][0] = __builtin_amdgcn_mfma_f32_16x16x32_bf16(b0u.s, a.s, acc1[rr][0], 0, 0, 0);
                acc1[rr][1] = __builtin_amdgcn_mfma_f32_16x16x32_bf16(b1u.s, a.s, acc1[rr][1], 0, 0, 0);
            }
        }
    }
    __syncthreads();   // all feat reads done; s_feat can be overlaid with att*d

    // ------- Stage 3b: sigmoid + *d via packed dpk, write overlay (2x b64 per row) -------
    // lane owns pixel ax = mcol of att row ay; oc = 16h + 4q+reg.
    {
        const float* dpk = ws + WS_DPK;
        const int gx = tx * TILE - 1 + mcol;
        const bool gxok = (gx >= 0 && gx < ww);
        const int gxs = min(max(gx, 0), ww - 1);
        #pragma unroll
        for (int rr = 0; rr < 4; ++rr) {
            int ay = wv*4 + rr;
            int gy = ty * TILE - 1 + ay;
            bool ok = gxok && (gy >= 0 && gy < hh);
            int gys = min(max(gy, 0), hh - 1);
            const float* dp = dpk + ((size_t)((n*hh + gys)*ww + gxs)) * 32;
            f32x4 d0 = *(const f32x4*)(dp + 4*q);        // oc 4q..4q+3
            f32x4 d1 = *(const f32x4*)(dp + 16 + 4*q);   // oc 16+4q..
            if (!ok) { d0 = (f32x4){0,0,0,0}; d1 = (f32x4){0,0,0,0}; }
            float v0[4], v1[4];
            #pragma unroll
            for (int reg = 0; reg < 4; ++reg) {
                v0[reg] = __builtin_amdgcn_rcpf(1.f + __expf(-acc1[rr][0][reg])) * d0[reg];
                v1[reg] = __builtin_amdgcn_rcpf(1.f + __expf(-acc1[rr][1][reg])) * d1[reg];
            }
            int pix = ay * ATT + mcol;
            int sw2 = (pix >> 1) & 3;
            // cp 2q,2q+1 live in chunk q>>1 at dword offset (2q)&3; cp 8+2q in chunk 2+(q>>1)
            int dwA = pix * 16 + (((q >> 1)    ) ^ sw2) * 4 + ((2*q) & 3);
            int dwB = pix * 16 + (((q >> 1) + 2) ^ sw2) * 4 + ((2*q) & 3);
            uint2 pa; pa.x = bf16pack(v0[0], v0[1]); pa.y = bf16pack(v0[2], v0[3]);
            uint2 pb; pb.x = bf16pack(v1[0], v1[1]); pb.y = bf16pack(v1[2], v1[3]);
            *(uint2*)&s_feat[dwA] = pa;
            *(uint2*)&s_feat[dwB] = pb;
        }
    }
    __syncthreads();

    // ------- Stage 4: conv2 via MFMA (weights-first, hi/lo) + smooth-L1 epilogue ----
    // D: pixel qx = mcol, oc = 4q+reg (valid only q==0, reg=oc 0..3).
    float num_t = 0.f, den_t = 0.f;
    {
        const uint4* wB2 = (const uint4*)(ws + WS_WB2);
        const int qy0 = wv * 4;
        const f32x4 bias2v = *((const f32x4*)b_post);
        f32x4 acc2[4];
        #pragma unroll
        for (int rr = 0; rr < 4; ++rr) acc2[rr] = bias2v;
        #pragma unroll
        for (int t = 0; t < 9; ++t) {
            union { uint4 u; short8 s; } bh, bl;
            bh.u = wB2[(t*2 + 0)*64 + lane];
            bl.u = wB2[(t*2 + 1)*64 + lane];
            const int dy = t / 3, dx = t % 3;
            #pragma unroll
            for (int rr = 0; rr < 4; ++rr) {
                if (qy0 + rr >= TILE) break;        // uniform per wave
                int pix = (qy0 + rr + dy) * ATT + (mcol + dx);  // cols 16,17 bleed -> masked cols
                union { uint4 u; short8 s; } a;
                a.u = *(const uint4*)&s_feat[pix * 16 + (q ^ ((pix >> 1) & 3)) * 4];
                acc2[rr] = __builtin_amdgcn_mfma_f32_16x16x32_bf16(bh.s, a.s, acc2[rr], 0, 0, 0);
                acc2[rr] = __builtin_amdgcn_mfma_f32_16x16x32_bf16(bl.s, a.s, acc2[rr], 0, 0, 0);
            }
        }
        // epilogue: lane q==0 holds (qx=mcol, oc=reg); neighbor offsets compile-time per reg
        const bool colok = (q == 0) && (mcol < TILE) && (tx * TILE + mcol < ww);
        #pragma unroll
        for (int rr = 0; rr < 4; ++rr) {
            if (qy0 + rr >= TILE) break;
            int qy = qy0 + rr;
            bool rowok = (ty * TILE + qy < hh);
            float lc = s_plog[(qy + 2) * FT + (mcol + 2)];
            const int oys[4] = {0, 1, 1, 1};
            const int oxs[4] = {1, 1, 0, -1};
            #pragma unroll
            for (int reg = 0; reg < 4; ++reg) {
                float ln = s_plog[(qy + 2 + oys[reg]) * FT + (mcol + 2 + oxs[reg])];
                bool m = colok && rowok && (lc > MTHR) && (ln > MTHR);
                float a2 = fabsf(acc2[rr][reg] - (lc - ln));
                float sl1 = (a2 < 0.01f) ? (50.f * a2 * a2) : (a2 - 0.005f);
                if (m) { num_t += sl1; den_t += 1.f; }
            }
        }
    }

    for (int off = 32; off > 0; off >>= 1) {
        num_t += __shfl_down(num_t, off);
        den_t += __shfl_down(den_t, off);
    }
    if (lane == 0) { s_rn[wv] = num_t; s_rd[wv] = den_t; }
    __syncthreads();
    if (tid == 0) {
        int slot = r * 16 + (bb & 15);
        atomicAdd(&ws[WS_RED + slot*2],     s_rn[0] + s_rn[1] + s_rn[2] + s_rn[3]);
        atomicAdd(&ws[WS_RED + slot*2 + 1], s_rd[0] + s_rd[1] + s_rd[2] + s_rd[3]);
    }
}

// ---------------- fallback (used if ws too small) ----------------
__launch_bounds__(256, 6)
__global__ void wvl_fallback(const float* __restrict__ x, const float* __restrict__ d,
                             const float* __restrict__ gts, const float* __restrict__ rnd,
                             const float* __restrict__ b_att, const float* __restrict__ b_post,
                             float* __restrict__ ws) {
    __shared__ unsigned int s_buf[CP * FT * FT];
    __shared__ float s_pgt[FT * FT];
    __shared__ int   s_pidx[FT * FT];
    __shared__ float s_rn[4], s_rd[4];

    const float* w1t = ws + WS_W1T;
    const float* w2t = ws + WS_W2T;

    const int tid = threadIdx.x;
    const int tilesx = (ww + TILE - 1) / TILE;
    const int tx = blockIdx.x % tilesx;
    const int ty = blockIdx.x / tilesx;
    const int n  = blockIdx.y;
    const int r  = blockIdx.z;
    const int py0 = ty * TILE - 2;
    const int px0 = tx * TILE - 2;

    const float* gt_n = gts + (size_t)n * HH * WW;
    const float* rd_n = rnd + ((size_t)r * NN + n) * (size_t)(HH * WW);
    for (int p = tid; p < FT * FT; p += 256) {
        int pi = p / FT, pj = p % FT;
        int gi = py0 + pi, gj = px0 + pj;
        float gval = 0.f; int idx = -1;
        if (gi >= 0 && gi < hh && gj >= 0 && gj < ww) {
            float best = -1.f; int bii = 0, bjj = 0; float bg = 0.f;
            #pragma unroll
            for (int bi = 0; bi < 4; ++bi) {
                const float* gr = gt_n + (size_t)(gi*4 + bi) * WW + gj*4;
                const float* rp = rd_n + (size_t)(gi*4 + bi) * WW + gj*4;
                #pragma unroll
                for (int bj = 0; bj < 4; ++bj) {
                    float g  = gr[bj];
                    float rv = rp[bj];
                    float rm = (g > 0.1f) ? rv : 0.f;
                    if (rm > best) { best = rm; bii = bi; bjj = bj; bg = g; }
                }
            }
            gval = bg;
            idx = (gi*4 + bii) * WW + (gj*4 + bjj) + BIAS_IDX;
        }
        s_pgt[p]  = gval;
        s_pidx[p] = idx;
    }
    __syncthreads();

    const float* x_n = x + (size_t)n * FC * HH * WW;
    for (int p = tid; p < FT * FT; p += 256) {
        int idx = s_pidx[p];
        if (idx < 0) {
            #pragma unroll
            for (int cp = 0; cp < CP; ++cp) s_buf[cp * (FT*FT) + p] = 0u;
            continue;
        }
        int cc = idx % WW;
        int rr2 = idx / WW;
        float gxf = 2.0f * ((float)cc  / (float)WW - 0.5f);
        float gyf = 2.0f * ((float)rr2 / (float)HH - 0.5f);
        float ix = (gxf + 1.0f) * 0.5f * (float)(WW - 1);
        float iy = (gyf + 1.0f) * 0.5f * (float)(HH - 1);
        float x0f = floorf(ix), y0f = floorf(iy);
        float wx = ix - x0f, wy = iy - y0f;
        int x0 = (int)x0f, y0 = (int)y0f;
        float vx0 = (x0f >= 0.f        && x0f <= (float)(WW-1)) ? 1.f : 0.f;
        float vx1 = (x0f + 1.f >= 0.f  && x0f + 1.f <= (float)(WW-1)) ? 1.f : 0.f;
        float vy0 = (y0f >= 0.f        && y0f <= (float)(HH-1)) ? 1.f : 0.f;
        float vy1 = (y0f + 1.f >= 0.f  && y0f + 1.f <= (float)(HH-1)) ? 1.f : 0.f;
        int xi0 = min(max(x0, 0), WW-1),  xi1 = min(max(x0+1, 0), WW-1);
        int yi0 = min(max(y0, 0), HH-1),  yi1 = min(max(y0+1, 0), HH-1);
        float w00 = (1.f-wx)*(1.f-wy) * (vx0*vy0);
        float w10 = wx*(1.f-wy)       * (vx1*vy0);
        float w01 = (1.f-wx)*wy       * (vx0*vy1);
        float w11 = wx*wy             * (vx1*vy1);
        const float* p00 = x_n + (size_t)yi0 * WW + xi0;
        const float* p10 = x_n + (size_t)yi0 * WW + xi1;
        const float* p01 = x_n + (size_t)yi1 * WW + xi0;
        const float* p11 = x_n + (size_t)yi1 * WW + xi1;
        #pragma unroll 4
        for (int cp = 0; cp < CP; ++cp) {
            int o0 = (2*cp)     * (HH * WW);
            int o1 = (2*cp + 1) * (HH * WW);
            float f0 = w00 * p00[o0] + w10 * p10[o0] + w01 * p01[o0] + w11 * p11[o0];
            float f1 = w00 * p00[o1] + w10 * p10[o1] + w01 * p01[o1] + w11 * p11[o1];
            s_buf[cp * (FT*FT) + p] = bf16pack(f0, f1);
        }
    }
    __syncthreads();

    const int ay = tid >> 4, ax = tid & 15;
    float acc[32];
    #pragma unroll
    for (int oc = 0; oc < 32; ++oc) acc[oc] = b_att[oc];
    for (int dy = 0; dy < 3; ++dy) {
        for (int dx = 0; dx < 3; ++dx) {
            const float* wt = w1t + (dy*3 + dx) * 1024;
            int base = (ay + dy) * FT + (ax + dx);
            for (int cp = 0; cp < CP; ++cp) {
                unsigned int u = s_buf[cp * (FT*FT) + base];
                float f0 = __uint_as_float(u << 16);
                float f1 = __uint_as_float(u & 0xffff0000u);
                const float* wp0 = wt + (2*cp) * 32;
                const float* wp1 = wp0 + 32;
                #pragma unroll
                for (int oc = 0; oc < 32; ++oc) acc[oc] = fmaf(f0, wp0[oc], acc[oc]);
                #pragma unroll
                for (int oc = 0; oc < 32; ++oc) acc[oc] = fmaf(f1, wp1[oc], acc[oc]);
            }
        }
    }
    __syncthreads();
    {
        int gy = ty * TILE - 1 + ay;
        int gx = tx * TILE - 1 + ax;
        bool inb = (gy >= 0 && gy < hh && gx >= 0 && gx < ww);
        const float* d_n = d + (size_t)n * DC * hh * ww;
        #pragma unroll
        for (int cp = 0; cp < CP; ++cp) {
            float a0 = 1.f / (1.f + __expf(-acc[2*cp]));
            float a1 = 1.f / (1.f + __expf(-acc[2*cp+1]));
            float v0 = 0.f, v1 = 0.f;
            if (inb) {
                v0 = a0 * d_n[(size_t)((2*cp)   * hh + gy) * ww + gx];
                v1 = a1 * d_n[(size_t)((2*cp+1) * hh + gy) * ww + gx];
            }
            s_buf[cp * (ATT*ATT) + tid] = bf16pack(v0, v1);
        }
    }
    __syncthreads();

    float num_t = 0.f, den_t = 0.f;
    if (tid < TILE * TILE) {
        int qy = tid / TILE, qx = tid % TILE;
        int gy2 = ty * TILE + qy, gx2 = tx * TILE + qx;
        if (gy2 < hh && gx2 < ww) {
            float acc2[4];
            #pragma unroll
            for (int k = 0; k < 4; ++k) acc2[k] = b_post[k];
            for (int dy = 0; dy < 3; ++dy) {
                for (int dx = 0; dx < 3; ++dx) {
                    const float* wt = w2t + (dy*3 + dx) * 128;
                    int base = (qy + dy) * ATT + (qx + dx);
                    for (int cp = 0; cp < CP; ++cp) {
                        unsigned int u = s_buf[cp * (ATT*ATT) + base];
                        float f0 = __uint_as_float(u << 16);
                        float f1 = __uint_as_float(u & 0xffff0000u);
                        const float* wp0 = wt + (2*cp) * 4;
                        const float* wp1 = wp0 + 4;
                        #pragma unroll
                        for (int k2 = 0; k2 < 4; ++k2) acc2[k2] = fmaf(f0, wp0[k2], acc2[k2]);
                        #pragma unroll
                        for (int k2 = 0; k2 < 4; ++k2) acc2[k2] = fmaf(f1, wp1[k2], acc2[k2]);
                    }
                }
            }
            int pc = (qy + 2) * FT + (qx + 2);
            float rgc = s_pgt[pc]; rgc = (rgc < 0.1f) ? 0.f : rgc;
            float lc = logf(rgc + 1e-6f);
            bool  mc = rgc > 0.1f;
            const int oys[4] = {0, 1, 1, 1};
            const int oxs[4] = {1, 1, 0, -1};
            #pragma unroll
            for (int k = 0; k < 4; ++k) {
                int pnb = (qy + 2 + oys[k]) * FT + (qx + 2 + oxs[k]);
                float rgn = s_pgt[pnb]; rgn = (rgn < 0.1f) ? 0.f : rgn;
                float ln = logf(rgn + 1e-6f);
                bool m = mc && (rgn > 0.1f);
                float gg = lc - ln;
                float a2 = fabsf(acc2[k] - gg);
                float sl1 = (a2 < 0.01f) ? (0.5f * a2 * a2 / 0.01f) : (a2 - 0.005f);
                if (m) { num_t += sl1; den_t += 1.f; }
            }
        }
    }
    for (int off = 32; off > 0; off >>= 1) {
        num_t += __shfl_down(num_t, off);
        den_t += __shfl_down(den_t, off);
    }
    int wid = tid >> 6, lane = tid & 63;
    if (lane == 0) { s_rn[wid] = num_t; s_rd[wid] = den_t; }
    __syncthreads();
    if (tid == 0) {
        int slot = r * 16 + (blockIdx.x & 15);
        atomicAdd(&ws[WS_RED + slot*2],     s_rn[0] + s_rn[1] + s_rn[2] + s_rn[3]);
        atomicAdd(&ws[WS_RED + slot*2 + 1], s_rd[0] + s_rd[1] + s_rd[2] + s_rd[3]);
    }
}

// reduce the RR*16 float2 slots -> loss
__global__ void finish_kernel(const float* __restrict__ ws, float* __restrict__ out) {
    __shared__ float sn[RR], sd[RR];
    const int tid = threadIdx.x;
    if (tid < RR) { sn[tid] = 0.f; sd[tid] = 0.f; }
    __syncthreads();
    if (tid < RR * 16) {
        int r2 = tid >> 4;
        atomicAdd(&sn[r2], ws[WS_RED + tid*2]);
        atomicAdd(&sd[r2], ws[WS_RED + tid*2 + 1]);
    }
    __syncthreads();
    if (tid == 0) {
        float s = 0.f;
        for (int r2 = 0; r2 < RR; ++r2) s += sn[r2] / sd[r2];
        out[0] = s / (float)RR;
    }
}

extern "C" void kernel_launch(void* const* d_in, const int* in_sizes, int n_in,
                              void* d_out, int out_size, void* d_ws, size_t ws_size,
                              hipStream_t stream) {
    const float* x      = (const float*)d_in[0];
    const float* d      = (const float*)d_in[1];
    const float* gts    = (const float*)d_in[2];
    const float* rnd    = (const float*)d_in[3];
    const float* W_att  = (const float*)d_in[4];
    const float* b_att  = (const float*)d_in[5];
    const float* W_post = (const float*)d_in[6];
    const float* b_post = (const float*)d_in[7];
    float* out = (float*)d_out;
    float* ws  = (float*)d_ws;

    const int tilesx = (ww + TILE - 1) / TILE;  // 12
    const int tilesy = (hh + TILE - 1) / TILE;  // 9

    if (ws_size >= WS_NEED_BYTES) {
        hipLaunchKernelGGL(setup_kernel, dim3(SETUP_NB), dim3(256), 0, stream,
                           x, d, gts, rnd, W_att, W_post, ws);
        unsigned int* xb = (unsigned int*)(ws + WS_XB);
        // 1-D swizzled grid: 72 groups x 120 blocks = 8640 = tilesx*tilesy*NN*RR
        hipLaunchKernelGGL(wvl_main, dim3(tilesx * tilesy * NN * RR), dim3(256), 0, stream,
                           xb, b_att, b_post, ws);
    } else {
        hipLaunchKernelGGL(setup_kernel, dim3(1), dim3(256), 0, stream,
                           x, d, gts, rnd, W_att, W_post, ws);   // block 0 = weight prep only
        dim3 grid2(tilesx * tilesy, NN, RR);
        hipLaunchKernelGGL(wvl_fallback, grid2, dim3(256), 0, stream,
                           x, d, gts, rnd, b_att, b_post, ws);
    }

    hipLaunchKernelGGL(finish_kernel, dim3(1), dim3(512), 0, stream, ws, out);
}